// Round 12
// baseline (542.377 us; speedup 1.0000x reference)
//
#include <hip/hip_runtime.h>
#include <hip/hip_bf16.h>

#define NTOK 16384
#define DDIM 512
#define MMEM 100
#define HWSZ 4096
#define QKVW 300

typedef __attribute__((ext_vector_type(8))) short short8v;   // 8 bf16
typedef __attribute__((ext_vector_type(4))) short short4v;   // 4 bf16
typedef __attribute__((ext_vector_type(4))) float f32x4;

__device__ __forceinline__ unsigned short f2bf(float x) {
  union { __hip_bfloat16 h; unsigned short u; } cv;
  cv.h = __float2bfloat16(x);
  return cv.u;
}
__device__ __forceinline__ float bf2f(unsigned short u) {
  union { unsigned int u; float f; } v; v.u = ((unsigned int)u) << 16;
  return v.f;
}

// ---------------------------------------------------------------------------
// feat + cvtw + zero merged. Blocks 0..511: fea read-once -> out copy + qnbf.
// Blocks 512..740: weights -> bf16. Blocks 741..1047: zero atomic targets.
__global__ __launch_bounds__(256) void feat_cvtw_k(
    const float* __restrict__ fea, unsigned short* __restrict__ qnbf,
    float* __restrict__ out,
    const float* __restrict__ W1, const float* __restrict__ W2,
    const float* __restrict__ W3, const float* __restrict__ Wq,
    const float* __restrict__ b1, const float* __restrict__ b2,
    unsigned short* __restrict__ Wcat, unsigned short* __restrict__ o3,
    unsigned short* __restrict__ oq, float* __restrict__ bcat,
    float* __restrict__ zbase) {
  if (blockIdx.x >= 741) {
    int zidx = (blockIdx.x - 741) * 256 + threadIdx.x;   // 78592 float4s
    if (zidx < 78592)
      ((float4*)zbase)[zidx] = make_float4(0.f, 0.f, 0.f, 0.f);
    return;
  }
  if (blockIdx.x >= 512) {
    int base = (blockIdx.x - 512) * 256 + threadIdx.x;
    for (int idx = base; idx < 467968; idx += 229 * 256) {
      if (idx < 262144) {
        int k = idx >> 9, n = idx & 511;
        Wcat[(size_t)k * 1024 + n] = f2bf(W1[idx]);
        Wcat[(size_t)k * 1024 + 512 + n] = f2bf(W2[idx]);
      } else if (idx < 313344) {
        o3[idx - 262144] = f2bf(W3[idx - 262144]);
      } else if (idx < 466944) {
        oq[idx - 313344] = f2bf(Wq[idx - 313344]);
      } else {
        int i = idx - 466944;
        bcat[i] = (i < 512) ? b1[i] : b2[i - 512];
      }
    }
    return;
  }
  __shared__ float tile[512][33];
  __shared__ float psum[8][32];
  __shared__ float invn_s[32];
  const int bid = blockIdx.x;                 // 512
  const int b = bid >> 7, hw0 = (bid & 127) * 32;
  const int t = threadIdx.x;
  const int hwo = t & 31, cg = t >> 5;
  const float* src = fea + (size_t)b * DDIM * HWSZ + hw0;
  float* dst = out + (size_t)b * (2 * DDIM) * HWSZ + hw0;
  float ss = 0.f;
#pragma unroll 8
  for (int i = 0; i < 64; ++i) {
    int c = cg * 64 + i;
    float v = src[(size_t)c * HWSZ + hwo];
    tile[c][hwo] = v;
    dst[(size_t)c * HWSZ + hwo] = v;
    ss += v * v;
  }
  psum[cg][hwo] = ss;
  __syncthreads();
  if (t < 32) {
    float s = 0.f;
#pragma unroll
    for (int j = 0; j < 8; ++j) s += psum[j][t];
    invn_s[t] = 1.f / fmaxf(sqrtf(s), 1e-12f);
  }
  __syncthreads();
  const int tok = t & 31, c0 = (t >> 5) * 64;
  const float inv = invn_s[tok];
  unsigned short* qp = qnbf + ((size_t)(b * HWSZ + hw0 + tok)) * DDIM + c0;
#pragma unroll
  for (int e8 = 0; e8 < 8; ++e8) {
    short8v p;
#pragma unroll
    for (int e = 0; e < 8; ++e)
      p[e] = (short)f2bf(tile[c0 + e8 * 8 + e][tok] * inv);
    *(short8v*)(qp + e8 * 8) = p;
  }
}

// ---------------------------------------------------------------------------
// Device body: bf16 MFMA GEMM tile (128x128), bf16 out. smem: As@0, Bs@10240.
__device__ __forceinline__ void gemm_body(
    char* smem, const unsigned short* __restrict__ A,
    const unsigned short* __restrict__ B, const float* __restrict__ bias,
    unsigned short* __restrict__ Cbf,
    int M, int N, int K, int lda, int ldb, int ldc, int bx, int by) {
  unsigned short (*As)[40] = (unsigned short(*)[40])smem;
  unsigned short (*Bs)[132] = (unsigned short(*)[132])(smem + 10240);
  const int tid = threadIdx.x;
  const int l = tid & 63, w = tid >> 6;
  const int l15 = l & 15, lhi = l >> 4;
  const int wm = w >> 1, wn = w & 1;
  const int row0 = by * 128, col0 = bx * 128;
  const int am = tid >> 1, akq = (tid & 1) << 4;
  const int bk = tid >> 3, bnq = (tid & 7) << 4;
  const int arow = row0 + am;
  f32x4 acc[4][4] = {};

  for (int k0 = 0; k0 < K; k0 += 32) {
    short8v av0 = {}, av1 = {}, bv0 = {}, bv1 = {};
    if (arow < M && k0 + akq < K) {
      const unsigned short* ap = A + (size_t)arow * lda + k0 + akq;
      if (k0 + akq + 15 < K) {
        av0 = *(const short8v*)ap;
        av1 = *(const short8v*)(ap + 8);
      } else {
#pragma unroll
        for (int e = 0; e < 8; ++e) {
          av0[e] = (k0 + akq + e < K) ? (short)ap[e] : (short)0;
          av1[e] = (k0 + akq + 8 + e < K) ? (short)ap[8 + e] : (short)0;
        }
      }
    }
    {
      const int kk = k0 + bk;
      if (kk < K) {
        const unsigned short* bp = B + (size_t)kk * ldb + col0 + bnq;
        if (col0 + bnq + 15 < N) {
          bv0 = *(const short8v*)bp;
          bv1 = *(const short8v*)(bp + 8);
        } else {
#pragma unroll
          for (int e = 0; e < 8; ++e) {
            bv0[e] = (col0 + bnq + e < N) ? (short)bp[e] : (short)0;
            bv1[e] = (col0 + bnq + 8 + e < N) ? (short)bp[8 + e] : (short)0;
          }
        }
      }
    }
    __syncthreads();
    *(short8v*)&As[am][akq] = av0;
    *(short8v*)&As[am][akq + 8] = av1;
    *(short8v*)&Bs[bk][bnq] = bv0;
    *(short8v*)&Bs[bk][bnq + 8] = bv1;
    __syncthreads();
    short8v af[4];
#pragma unroll
    for (int mt = 0; mt < 4; ++mt)
      af[mt] = *(const short8v*)&As[wm * 64 + mt * 16 + l15][lhi * 8];
#pragma unroll
    for (int ct = 0; ct < 4; ++ct) {
      union { short8v v; unsigned short u[8]; } bf;
      const int nn = wn * 64 + ct * 16 + l15;
#pragma unroll
      for (int j = 0; j < 8; ++j) bf.u[j] = Bs[lhi * 8 + j][nn];
#pragma unroll
      for (int mt = 0; mt < 4; ++mt)
        acc[mt][ct] = __builtin_amdgcn_mfma_f32_16x16x32_bf16(
            af[mt], bf.v, acc[mt][ct], 0, 0, 0);
    }
  }

#pragma unroll
  for (int mt = 0; mt < 4; ++mt) {
    const int rb = row0 + wm * 64 + mt * 16 + lhi * 4;
#pragma unroll
    for (int u = 0; u < 4; ++u) {
      const int r = rb + u;
      if (r >= M) continue;
#pragma unroll
      for (int ct = 0; ct < 4; ++ct) {
        const int c = col0 + wn * 64 + ct * 16 + l15;
        if (c >= N) continue;
        float val = acc[mt][ct][u];
        if (bias) val += bias[c];
        Cbf[(size_t)r * ldc + c] = f2bf(val);
      }
    }
  }
}

// Device body: N=100 GEMM (K=512) + fused row-softmax -> bf16 probs.
__device__ __forceinline__ void sm100_body(
    char* smem, const unsigned short* __restrict__ A,
    const unsigned short* __restrict__ B, const float* __restrict__ bias,
    unsigned short* __restrict__ obf, int lda, int ldb, int ldo, int rowblk) {
  unsigned short (*As)[40] = (unsigned short(*)[40])smem;
  unsigned short (*Bs)[132] = (unsigned short(*)[132])(smem + 10240);
  unsigned short (*Ps)[104] = (unsigned short(*)[104])smem;
  const int tid = threadIdx.x;
  const int l = tid & 63, w = tid >> 6;
  const int l15 = l & 15, lhi = l >> 4;
  const int wm = w >> 1, wn = w & 1;
  const int row0 = rowblk * 128;
  const int am = tid >> 1, akq = (tid & 1) << 4;
  const int bk = tid >> 3, bnq = (tid & 7) << 4;
  f32x4 acc[4][4] = {};

  for (int k0 = 0; k0 < DDIM; k0 += 32) {
    const unsigned short* ap = A + (size_t)(row0 + am) * lda + k0 + akq;
    short8v av0 = *(const short8v*)ap;
    short8v av1 = *(const short8v*)(ap + 8);
    short8v bv0 = {}, bv1 = {};
    const unsigned short* bp = B + (size_t)(k0 + bk) * ldb + bnq;
    if (bnq + 15 < MMEM) {
      bv0 = *(const short8v*)bp;
      bv1 = *(const short8v*)(bp + 8);
    } else {
#pragma unroll
      for (int e = 0; e < 8; ++e) {
        bv0[e] = (bnq + e < MMEM) ? (short)bp[e] : (short)0;
        bv1[e] = (bnq + 8 + e < MMEM) ? (short)bp[8 + e] : (short)0;
      }
    }
    __syncthreads();
    *(short8v*)&As[am][akq] = av0;
    *(short8v*)&As[am][akq + 8] = av1;
    *(short8v*)&Bs[bk][bnq] = bv0;
    *(short8v*)&Bs[bk][bnq + 8] = bv1;
    __syncthreads();
    short8v af[4];
#pragma unroll
    for (int mt = 0; mt < 4; ++mt)
      af[mt] = *(const short8v*)&As[wm * 64 + mt * 16 + l15][lhi * 8];
#pragma unroll
    for (int ct = 0; ct < 4; ++ct) {
      union { short8v v; unsigned short u[8]; } bf;
      const int nn = wn * 64 + ct * 16 + l15;
#pragma unroll
      for (int j = 0; j < 8; ++j) bf.u[j] = Bs[lhi * 8 + j][nn];
#pragma unroll
      for (int mt = 0; mt < 4; ++mt)
        acc[mt][ct] = __builtin_amdgcn_mfma_f32_16x16x32_bf16(
            af[mt], bf.v, acc[mt][ct], 0, 0, 0);
    }
  }

  __syncthreads();   // As/Bs dead; Ps overlays them
#pragma unroll
  for (int mt = 0; mt < 4; ++mt) {
#pragma unroll
    for (int u = 0; u < 4; ++u) {
      const int r = wm * 64 + mt * 16 + lhi * 4 + u;
#pragma unroll
      for (int ct = 0; ct < 4; ++ct) {
        const int c = wn * 64 + ct * 16 + l15;
        if (c < MMEM) {
          float val = acc[mt][ct][u];
          if (bias) val += bias[c];
          Ps[r][c] = f2bf(val);
        }
      }
    }
  }
  __syncthreads();
  for (int rr = 0; rr < 32; ++rr) {
    const int r = w * 32 + rr;
    float v0 = bf2f(Ps[r][l]);
    const bool has1 = (l + 64) < MMEM;
    float v1 = has1 ? bf2f(Ps[r][l + 64]) : -3.4e38f;
    float m = fmaxf(v0, v1);
#pragma unroll
    for (int o = 32; o; o >>= 1) m = fmaxf(m, __shfl_xor(m, o, 64));
    float e0 = expf(v0 - m);
    float e1 = has1 ? expf(v1 - m) : 0.f;
    float s = e0 + e1;
#pragma unroll
    for (int o = 32; o; o >>= 1) s += __shfl_xor(s, o, 64);
    float inv = 1.f / s;
    unsigned short* orow = obf + (size_t)(row0 + r) * ldo;
    orow[l] = f2bf(e0 * inv);
    if (has1) orow[l + 64] = f2bf(e1 * inv);
  }
}

// Device body: C(MxN) += A^T @ B over K-chunk (atomic f32 C).
// mirror: also atomicAdd transposed element (symmetric outputs, off-diag tiles).
__device__ __forceinline__ void atb_body(
    char* smem, const unsigned short* __restrict__ A,
    const unsigned short* __restrict__ B, float* __restrict__ C,
    int M, int N, int K, int lda, int ldb, int ldc, int KC,
    int bx, int by, int bz, bool mirror) {
  unsigned short (*As)[40] = (unsigned short(*)[40])smem;
  unsigned short (*Bs)[132] = (unsigned short(*)[132])(smem + 10240);
  const int tid = threadIdx.x;
  const int l = tid & 63, w = tid >> 6;
  const int l15 = l & 15, lhi = l >> 4;
  const int wm = w >> 1, wn = w & 1;
  const int row0 = by * 128, col0 = bx * 128;
  const int kbeg = bz * KC;
  const int kend = min(kbeg + KC, K);
  const int akk = tid >> 3, amq = (tid & 7) << 4;
  const int bk = tid >> 3, bnq = (tid & 7) << 4;
  f32x4 acc[4][4] = {};

  for (int k0 = kbeg; k0 < kend; k0 += 32) {
    unsigned short av[16]; short8v bv0 = {}, bv1 = {};
    {
      const int kk = k0 + akk;
      if (kk < kend) {
        const unsigned short* ap = A + (size_t)kk * lda + row0 + amq;
        if (row0 + amq + 15 < M) {
          *(short8v*)&av[0] = *(const short8v*)ap;
          *(short8v*)&av[8] = *(const short8v*)(ap + 8);
        } else {
#pragma unroll
          for (int e = 0; e < 16; ++e)
            av[e] = (row0 + amq + e < M) ? ap[e] : 0;
        }
      } else {
#pragma unroll
        for (int e = 0; e < 16; ++e) av[e] = 0;
      }
    }
    {
      const int kk = k0 + bk;
      if (kk < kend) {
        const unsigned short* bp = B + (size_t)kk * ldb + col0 + bnq;
        if (col0 + bnq + 15 < N) {
          bv0 = *(const short8v*)bp;
          bv1 = *(const short8v*)(bp + 8);
        } else {
#pragma unroll
          for (int e = 0; e < 8; ++e) {
            bv0[e] = (col0 + bnq + e < N) ? (short)bp[e] : (short)0;
            bv1[e] = (col0 + bnq + 8 + e < N) ? (short)bp[8 + e] : (short)0;
          }
        }
      }
    }
    __syncthreads();
#pragma unroll
    for (int e = 0; e < 16; ++e) As[amq + e][akk] = av[e];   // transposed
    *(short8v*)&Bs[bk][bnq] = bv0;
    *(short8v*)&Bs[bk][bnq + 8] = bv1;
    __syncthreads();
    short8v af[4];
#pragma unroll
    for (int mt = 0; mt < 4; ++mt)
      af[mt] = *(const short8v*)&As[wm * 64 + mt * 16 + l15][lhi * 8];
#pragma unroll
    for (int ct = 0; ct < 4; ++ct) {
      union { short8v v; unsigned short u[8]; } bf;
      const int nn = wn * 64 + ct * 16 + l15;
#pragma unroll
      for (int j = 0; j < 8; ++j) bf.u[j] = Bs[lhi * 8 + j][nn];
#pragma unroll
      for (int mt = 0; mt < 4; ++mt)
        acc[mt][ct] = __builtin_amdgcn_mfma_f32_16x16x32_bf16(
            af[mt], bf.v, acc[mt][ct], 0, 0, 0);
    }
  }

#pragma unroll
  for (int mt = 0; mt < 4; ++mt) {
    const int rb = row0 + wm * 64 + mt * 16 + lhi * 4;
#pragma unroll
    for (int u = 0; u < 4; ++u) {
      const int r = rb + u;
      if (r >= M) continue;
#pragma unroll
      for (int ct = 0; ct < 4; ++ct) {
        const int c = col0 + wn * 64 + ct * 16 + l15;
        if (c >= N) continue;
        atomicAdd(&C[(size_t)r * ldc + c], acc[mt][ct][u]);
        if (mirror) atomicAdd(&C[(size_t)c * ldc + r], acc[mt][ct][u]);
      }
    }
  }
}

// ---------------------------------------------------------------------------
// step2: ip12 GEMM (blocks 0..1023) || ip3 GEMM+softmax (1024..1151)
__global__ __launch_bounds__(256) void step2_k(
    const unsigned short* __restrict__ qnbf, const unsigned short* __restrict__ Wcat,
    const float* __restrict__ bcat, unsigned short* __restrict__ ip12bf,
    const unsigned short* __restrict__ W3bf, const float* __restrict__ b3,
    unsigned short* __restrict__ ip3bf) {
  __shared__ char smem[26624];
  const int bid = blockIdx.x;
  if (bid < 1024) {
    gemm_body(smem, qnbf, Wcat, bcat, ip12bf, NTOK, 1024, DDIM,
              DDIM, 1024, 1024, bid & 7, bid >> 3);
  } else {
    sm100_body(smem, qnbf, W3bf, b3, ip3bf, DDIM, MMEM, MMEM, bid - 1024);
  }
}

// step3: atb_item symmetric 10 tiles (0..319) || atb_S (320..575) || colsum (576..831)
__global__ __launch_bounds__(256) void step3_k(
    const unsigned short* __restrict__ ip12bf, const unsigned short* __restrict__ ip3bf,
    float* __restrict__ item, float* __restrict__ S, float* __restrict__ ip2sum) {
  __shared__ char smem[18688];
  const int bid = blockIdx.x;
  const int t = threadIdx.x;
  if (bid < 320) {
    // upper-triangle tile list: 4 diagonal + 6 off-diagonal (bx > by)
    const int tabx[10] = {0, 1, 2, 3, 1, 2, 3, 2, 3, 3};
    const int taby[10] = {0, 1, 2, 3, 0, 0, 0, 1, 1, 2};
    const int p = bid >> 5, bz = bid & 31;
    atb_body(smem, ip12bf, ip12bf, item, DDIM, DDIM, NTOK,
             1024, 1024, DDIM, 512, tabx[p], taby[p], bz, tabx[p] != taby[p]);
  } else if (bid < 576) {
    const int b2 = bid - 320;
    atb_body(smem, ip3bf, ip12bf + 512, S, MMEM, DDIM, NTOK,
             MMEM, 1024, DDIM, 256, b2 & 3, 0, b2 >> 2, false);
  } else {
    const int cb = bid - 576;   // 0..255, 64 rows each
    const unsigned short* p = ip12bf + 512 + (size_t)cb * 64 * 1024 + t;
    float a0 = 0.f, a1 = 0.f, a2 = 0.f, a3 = 0.f;
    float b0 = 0.f, b1 = 0.f, b2 = 0.f, b3 = 0.f;
    for (int r = 0; r < 64; r += 4) {
      a0 += bf2f(p[(size_t)(r + 0) * 1024]); b0 += bf2f(p[(size_t)(r + 0) * 1024 + 256]);
      a1 += bf2f(p[(size_t)(r + 1) * 1024]); b1 += bf2f(p[(size_t)(r + 1) * 1024 + 256]);
      a2 += bf2f(p[(size_t)(r + 2) * 1024]); b2 += bf2f(p[(size_t)(r + 2) * 1024 + 256]);
      a3 += bf2f(p[(size_t)(r + 3) * 1024]); b3 += bf2f(p[(size_t)(r + 3) * 1024 + 256]);
    }
    atomicAdd(&ip2sum[t], (a0 + a1) + (a2 + a3));
    atomicAdd(&ip2sum[t + 256], (b0 + b1) + (b2 + b3));
  }
}

// ---------------------------------------------------------------------------
// step4: ip4sum (0..799) || qkv_base GEMM (800..811) || t2 = ip2sum^T @ Wqkv (812)
__global__ __launch_bounds__(256) void step4_k(
    const float* __restrict__ S, const float* __restrict__ rel_w,
    float* __restrict__ ip4sum,
    const float* __restrict__ item, const float* __restrict__ item_w,
    const unsigned short* __restrict__ Wqbf, const float* __restrict__ bqkv,
    float* __restrict__ qkv,
    const float* __restrict__ ip2sum, const float* __restrict__ Wqkv,
    float* __restrict__ t2) {
  __shared__ char smem[18688];
  const int bid = blockIdx.x;
  const int tid = threadIdx.x;
  if (bid < 800) {
    // ip4sum: 64 flat rows per block
    float* sv = (float*)smem;
    int r0 = bid * 64;
    if (tid < 64) sv[tid] = S[r0 + tid];
    __syncthreads();
    float a0 = 0.f, a1 = 0.f, a2 = 0.f, a3 = 0.f;
    float b0 = 0.f, b1 = 0.f, b2 = 0.f, b3 = 0.f;
    const float* base = rel_w + (size_t)r0 * DDIM;
    for (int r = 0; r < 64; r += 4) {
      const float* p0 = base + (size_t)(r + 0) * DDIM;
      const float* p1 = base + (size_t)(r + 1) * DDIM;
      const float* p2 = base + (size_t)(r + 2) * DDIM;
      const float* p3 = base + (size_t)(r + 3) * DDIM;
      a0 = fmaf(sv[r + 0], p0[tid], a0); b0 = fmaf(sv[r + 0], p0[tid + 256], b0);
      a1 = fmaf(sv[r + 1], p1[tid], a1); b1 = fmaf(sv[r + 1], p1[tid + 256], b1);
      a2 = fmaf(sv[r + 2], p2[tid], a2); b2 = fmaf(sv[r + 2], p2[tid + 256], b2);
      a3 = fmaf(sv[r + 3], p3[tid], a3); b3 = fmaf(sv[r + 3], p3[tid + 256], b3);
    }
    atomicAdd(&ip4sum[tid], (a0 + a1) + (a2 + a3));
    atomicAdd(&ip4sum[tid + 256], (b0 + b1) + (b2 + b3));
    return;
  }
  if (bid == 812) {
    // t2[n] = sum_d ip2sum[d] * Wqkv[d, n]   (f32, tiny)
    for (int n = tid; n < QKVW; n += 256) {
      float s = 0.f;
      for (int d = 0; d < DDIM; ++d) s = fmaf(ip2sum[d], Wqkv[(size_t)d * QKVW + n], s);
      t2[n] = s;
    }
    return;
  }
  // qkv_base = (item + item_w) @ Wqbf + bqkv  (rank-1 term folded into ln300)
  {
    unsigned short (*As)[40] = (unsigned short(*)[40])smem;
    unsigned short (*Bs)[132] = (unsigned short(*)[132])(smem + 10240);
    const int qb = bid - 800;                 // 0..11
    const int bx = qb % 3, by = qb / 3;
    const int l = tid & 63, w = tid >> 6;
    const int l15 = l & 15, lhi = l >> 4;
    const int wm = w >> 1, wn = w & 1;
    const int row0 = by * 128, col0 = bx * 128;
    const int am = tid >> 1, akq = (tid & 1) << 4;
    const int bk = tid >> 3, bnq = (tid & 7) << 4;
    const int arow = row0 + am;
    f32x4 acc[4][4] = {};

    for (int k0 = 0; k0 < DDIM; k0 += 32) {
      float av[16];
      {
        const size_t off = (size_t)arow * DDIM + k0 + akq;
#pragma unroll
        for (int u = 0; u < 4; ++u) {
          float4 a = *(const float4*)(item + off + 4 * u);
          float4 b = *(const float4*)(item_w + off + 4 * u);
          av[4*u+0] = a.x + b.x;
          av[4*u+1] = a.y + b.y;
          av[4*u+2] = a.z + b.z;
          av[4*u+3] = a.w + b.w;
        }
      }
      short8v bv0 = {}, bv1 = {};
      {
        const int kk = k0 + bk;
        const unsigned short* bp = Wqbf + (size_t)kk * QKVW + col0 + bnq;
        if (col0 + bnq + 15 < QKVW) {
          bv0 = *(const short8v*)bp;
          bv1 = *(const short8v*)(bp + 8);
        } else {
#pragma unroll
          for (int e = 0; e < 8; ++e) {
            bv0[e] = (col0 + bnq + e < QKVW) ? (short)bp[e] : (short)0;
            bv1[e] = (col0 + bnq + 8 + e < QKVW) ? (short)bp[8 + e] : (short)0;
          }
        }
      }
      __syncthreads();
      {
        short8v p0, p1;
#pragma unroll
        for (int e = 0; e < 8; ++e) p0[e] = (short)f2bf(av[e]);
#pragma unroll
        for (int e = 0; e < 8; ++e) p1[e] = (short)f2bf(av[8 + e]);
        *(short8v*)&As[am][akq] = p0;
        *(short8v*)&As[am][akq + 8] = p1;
      }
      *(short8v*)&Bs[bk][bnq] = bv0;
      *(short8v*)&Bs[bk][bnq + 8] = bv1;
      __syncthreads();
      short8v af[4];
#pragma unroll
      for (int mt = 0; mt < 4; ++mt)
        af[mt] = *(const short8v*)&As[wm * 64 + mt * 16 + l15][lhi * 8];
#pragma unroll
      for (int ct = 0; ct < 4; ++ct) {
        union { short8v v; unsigned short u[8]; } bf;
        const int nn = wn * 64 + ct * 16 + l15;
#pragma unroll
        for (int j = 0; j < 8; ++j) bf.u[j] = Bs[lhi * 8 + j][nn];
#pragma unroll
        for (int mt = 0; mt < 4; ++mt)
          acc[mt][ct] = __builtin_amdgcn_mfma_f32_16x16x32_bf16(
              af[mt], bf.v, acc[mt][ct], 0, 0, 0);
      }
    }

#pragma unroll
    for (int mt = 0; mt < 4; ++mt) {
      const int rb = row0 + wm * 64 + mt * 16 + lhi * 4;
#pragma unroll
      for (int u = 0; u < 4; ++u) {
        const int r = rb + u;
#pragma unroll
        for (int ct = 0; ct < 4; ++ct) {
          const int c = col0 + wn * 64 + ct * 16 + l15;
          if (c >= QKVW) continue;
          qkv[(size_t)r * QKVW + c] = acc[mt][ct][u] + bqkv[c];
        }
      }
    }
  }
}

// addr GEMM + softmax (standalone)
__global__ __launch_bounds__(256) void sm100_addr_k(
    const unsigned short* __restrict__ qnbf, const unsigned short* __restrict__ mnTbf,
    unsigned short* __restrict__ addrbf) {
  __shared__ char smem[26624];
  sm100_body(smem, qnbf, mnTbf, nullptr, addrbf, DDIM, MMEM, 128, blockIdx.x);
}

// ---------------------------------------------------------------------------
// mf GEMM writing out directly (channel-major) via LDS bf16 transpose epilogue.
__global__ __launch_bounds__(256) void gemm_mf_out_k(
    const unsigned short* __restrict__ A, const unsigned short* __restrict__ B,
    float* __restrict__ out) {
  __shared__ char smem[35328];
  unsigned short (*As)[40] = (unsigned short(*)[40])smem;
  unsigned short (*Bs)[132] = (unsigned short(*)[132])(smem + 10240);
  unsigned short (*Ps)[138] = (unsigned short(*)[138])smem;  // overlay after loop
  const int tid = threadIdx.x;
  const int l = tid & 63, w = tid >> 6;
  const int l15 = l & 15, lhi = l >> 4;
  const int wm = w >> 1, wn = w & 1;
  const int row0 = blockIdx.y * 128, col0 = blockIdx.x * 128;
  const int am = tid >> 1, akq = (tid & 1) << 4;
  const int bk = tid >> 3, bnq = (tid & 7) << 4;
  const int K = MMEM, lda = 128, ldb = DDIM;
  f32x4 acc[4][4] = {};

  for (int k0 = 0; k0 < 128; k0 += 32) {
    short8v av0 = {}, av1 = {}, bv0 = {}, bv1 = {};
    if (k0 + akq < K) {
      const unsigned short* ap = A + (size_t)(row0 + am) * lda + k0 + akq;
      if (k0 + akq + 15 < K) {
        av0 = *(const short8v*)ap;
        av1 = *(const short8v*)(ap + 8);
      } else {
#pragma unroll
        for (int e = 0; e < 8; ++e) {
          av0[e] = (k0 + akq + e < K) ? (short)ap[e] : (short)0;
          av1[e] = (k0 + akq + 8 + e < K) ? (short)ap[8 + e] : (short)0;
        }
      }
    }
    {
      const int kk = k0 + bk;
      if (kk < K) {
        const unsigned short* bp = B + (size_t)kk * ldb + col0 + bnq;
        bv0 = *(const short8v*)bp;
        bv1 = *(const short8v*)(bp + 8);
      }
    }
    __syncthreads();
    *(short8v*)&As[am][akq] = av0;
    *(short8v*)&As[am][akq + 8] = av1;
    *(short8v*)&Bs[bk][bnq] = bv0;
    *(short8v*)&Bs[bk][bnq + 8] = bv1;
    __syncthreads();
    short8v af[4];
#pragma unroll
    for (int mt = 0; mt < 4; ++mt)
      af[mt] = *(const short8v*)&As[wm * 64 + mt * 16 + l15][lhi * 8];
#pragma unroll
    for (int ct = 0; ct < 4; ++ct) {
      union { short8v v; unsigned short u[8]; } bf;
      const int nn = wn * 64 + ct * 16 + l15;
#pragma unroll
      for (int j = 0; j < 8; ++j) bf.u[j] = Bs[lhi * 8 + j][nn];
#pragma unroll
      for (int mt = 0; mt < 4; ++mt)
        acc[mt][ct] = __builtin_amdgcn_mfma_f32_16x16x32_bf16(
            af[mt], bf.v, acc[mt][ct], 0, 0, 0);
    }
  }

  __syncthreads();   // As/Bs dead; Ps overlays
#pragma unroll
  for (int mt = 0; mt < 4; ++mt) {
#pragma unroll
    for (int u = 0; u < 4; ++u) {
      const int r = wm * 64 + mt * 16 + lhi * 4 + u;   // hw within tile
#pragma unroll
      for (int ct = 0; ct < 4; ++ct) {
        const int c = wn * 64 + ct * 16 + l15;          // channel within tile
        Ps[r][c] = f2bf(acc[mt][ct][u]);
      }
    }
  }
  __syncthreads();
  const int b = row0 >> 12;
  const int hwb = row0 & 4095;
  const int j = tid & 63;
  float* obase = out + (size_t)b * 4194304 + (size_t)(512 + col0) * HWSZ + hwb;
  for (int cr = tid >> 6; cr < 128; cr += 4) {
    obase[(size_t)cr * HWSZ + j]      = bf2f(Ps[j][cr]);
    obase[(size_t)cr * HWSZ + j + 64] = bf2f(Ps[j + 64][cr]);
  }
}

// ---------------------------------------------------------------------------
// rel0 via MFMA (known-good)
__global__ __launch_bounds__(256) void rel0_mfma_k(
    const float* __restrict__ qm, const float* __restrict__ km,
    const float* __restrict__ vm, const float* __restrict__ rel_w,
    unsigned short* __restrict__ relbf) {
  __shared__ unsigned short Ts[128][136];
  __shared__ unsigned short Vs[128][136];
  __shared__ float qv[128];
  const int i = blockIdx.y;
  const int d0 = blockIdx.x * 128;
  const int tid = threadIdx.x;
  const int l = tid & 63, w = tid >> 6;
  const int l15 = l & 15, lhi = l >> 4;
  const int wm = w >> 1, wn = w & 1;

  if (tid < 128) qv[tid] = qm[(size_t)i * DDIM + d0 + tid];
  __syncthreads();
#pragma unroll
  for (int p = 0; p < 8; ++p) {
    int g = p * 2048 + tid * 8;
    int j = g >> 7, dd = g & 127;
    if (j < MMEM) {
      const float* kp = km + (size_t)j * DDIM + d0 + dd;
      float4 k0v = *(const float4*)kp;
      float4 k1v = *(const float4*)(kp + 4);
      float kv[8] = {k0v.x, k0v.y, k0v.z, k0v.w, k1v.x, k1v.y, k1v.z, k1v.w};
#pragma unroll
      for (int e = 0; e < 8; ++e)
        Ts[dd + e][j] = f2bf(tanhf(qv[dd + e] * kv[e]));
    } else {
#pragma unroll
      for (int e = 0; e < 8; ++e) Ts[dd + e][j] = 0;
    }
  }

  for (int f0 = 0; f0 < DDIM; f0 += 128) {
    __syncthreads();
#pragma unroll
    for (int p = 0; p < 8; ++p) {
      int g = p * 2048 + tid * 8;
      int j = g >> 7, ff = g & 127;
      short8v pv;
      if (j < MMEM) {
        const float* vp = vm + (size_t)j * DDIM + f0 + ff;
        float4 v0 = *(const float4*)vp;
        float4 v1 = *(const float4*)(vp + 4);
        pv[0] = (short)f2bf(v0.x); pv[1] = (short)f2bf(v0.y);
        pv[2] = (short)f2bf(v0.z); pv[3] = (short)f2bf(v0.w);
        pv[4] = (short)f2bf(v1.x); pv[5] = (short)f2bf(v1.y);
        pv[6] = (short)f2bf(v1.z); pv[7] = (short)f2bf(v1.w);
      } else {
#pragma unroll
        for (int e = 0; e < 8; ++e) pv[e] = 0;
      }
      *(short8v*)&Vs[j][ff] = pv;
    }
    __syncthreads();
    f32x4 acc[4][4] = {};
#pragma unroll
    for (int ks = 0; ks < 4; ++ks) {
      const int kb = ks * 32;
      short8v af[4];
#pragma unroll
      for (int mt = 0; mt < 4; ++mt)
        af[mt] = *(const short8v*)&Ts[wm * 64 + mt * 16 + l15][kb + lhi * 8];
#pragma unroll
      for (int ct = 0; ct < 4; ++ct) {
        union { short8v v; unsigned short u[8]; } bf;
        const int nn = wn * 64 + ct * 16 + l15;
#pragma unroll
        for (int jj = 0; jj < 8; ++jj) bf.u[jj] = Vs[kb + lhi * 8 + jj][nn];
#pragma unroll
        for (int mt = 0; mt < 4; ++mt)
          acc[mt][ct] = __builtin_amdgcn_mfma_f32_16x16x32_bf16(
              af[mt], bf.v, acc[mt][ct], 0, 0, 0);
      }
    }
#pragma unroll
    for (int mt = 0; mt < 4; ++mt) {
#pragma unroll
      for (int u = 0; u < 4; ++u) {
        const int d = d0 + wm * 64 + mt * 16 + lhi * 4 + u;
        const size_t base = (size_t)i * 262144 + (size_t)d * DDIM;
#pragma unroll
        for (int ct = 0; ct < 4; ++ct) {
          const int f = f0 + wn * 64 + ct * 16 + l15;
          relbf[base + f] = f2bf(rel_w[base + f] + acc[mt][ct][u]);
        }
      }
    }
  }
}

// ---------------------------------------------------------------------------
// memgemm: 1024 threads (16 waves), KC=1024, 256 chunks, bf16 partials.
#define MGK 262144
#define MGKC 1024
#define MGCHUNK 256
__global__ __launch_bounds__(1024, 4) void memgemm_k(
    const unsigned short* __restrict__ Ag, const float* __restrict__ Bg,
    unsigned short* __restrict__ partial) {
  __shared__ unsigned short As[128][44];
  __shared__ unsigned short Bs[32][520];
  const int tid = threadIdx.x;
  const int l = tid & 63, w = tid >> 6;
  const int l15 = l & 15, lhi = l >> 4;
  const int kbeg = blockIdx.x * MGKC;
  const int arow = tid >> 3, akq = tid & 7;
  const int bk = tid >> 5, bnq = (tid & 31) * 16;
  const int bsw = ((bk >> 3) & 3) << 4;
  const int csw = lhi << 4;
  f32x4 acc[8][2] = {};

  for (int t32 = 0; t32 < MGKC / 32; ++t32) {
    const int kb = kbeg + t32 * 32;
    short4v av = {};
    if (arow < MMEM)
      av = *(const short4v*)(Ag + (size_t)arow * MGK + kb + akq * 4);
    float4 bv[4];
    const float* bp = Bg + (size_t)(kb + bk) * DDIM + bnq;
#pragma unroll
    for (int u = 0; u < 4; ++u) bv[u] = *(const float4*)(bp + 4 * u);
    __syncthreads();
    *(short4v*)&As[arow][akq * 4] = av;
#pragma unroll
    for (int u = 0; u < 2; ++u) {
      short8v pb;
      pb[0] = (short)f2bf(bv[2*u].x);   pb[1] = (short)f2bf(bv[2*u].y);
      pb[2] = (short)f2bf(bv[2*u].z);   pb[3] = (short)f2bf(bv[2*u].w);
      pb[4] = (short)f2bf(bv[2*u+1].x); pb[5] = (short)f2bf(bv[2*u+1].y);
      pb[6] = (short)f2bf(bv[2*u+1].z); pb[7] = (short)f2bf(bv[2*u+1].w);
      *(short8v*)&Bs[bk][(bnq + u * 8) ^ bsw] = pb;
    }
    __syncthreads();
    union { short8v v; unsigned short u[8]; } bf0, bf1;
    const int nn0 = w * 32 + l15, nn1 = w * 32 + 16 + l15;
#pragma unroll
    for (int j = 0; j < 8; ++j) {
      bf0.u[j] = Bs[lhi * 8 + j][nn0 ^ csw];
      bf1.u[j] = Bs[lhi * 8 + j][nn1 ^ csw];
    }
#pragma unroll
    for (int mt = 0; mt < 8; ++mt) {
      short8v af = *(const short8v*)&As[mt * 16 + l15][lhi * 8];
      acc[mt][0] = __builtin_amdgcn_mfma_f32_16x16x32_bf16(af, bf0.v, acc[mt][0], 0, 0, 0);
      acc[mt][1] = __builtin_amdgcn_mfma_f32_16x16x32_bf16(af, bf1.v, acc[mt][1], 0, 0, 0);
    }
  }

  unsigned short* pw = partial + (size_t)blockIdx.x * (MMEM * DDIM);
#pragma unroll
  for (int mt = 0; mt < 8; ++mt) {
    const int r0 = mt * 16 + lhi * 4;
#pragma unroll
    for (int r = 0; r < 4; ++r) {
      const int row = r0 + r;
      if (row < MMEM) {
        pw[(size_t)row * DDIM + w * 32 + l15]      = f2bf(acc[mt][0][r]);
        pw[(size_t)row * DDIM + w * 32 + 16 + l15] = f2bf(acc[mt][1][r]);
      }
    }
  }
}

// Fused reduce(256 bf16 partials) + br1 + l2norm -> mnbf/mnTbf (16 accumulators).
__global__ __launch_bounds__(512) void reduce_mn_k(
    const unsigned short* __restrict__ partial, const float* __restrict__ br1,
    unsigned short* __restrict__ mnbf, unsigned short* __restrict__ mnTbf) {
  __shared__ float r1[8];
  const int i = blockIdx.x, t = threadIdx.x;
  const unsigned short* p = partial + (size_t)i * DDIM + t;
  float a[16] = {};
  const size_t zs = (size_t)(MMEM * DDIM);
  for (int z = 0; z < MGCHUNK; z += 16) {
#pragma unroll
    for (int e = 0; e < 16; ++e) a[e] += bf2f(p[(z + e) * zs]);
  }
  float s = br1[t];
#pragma unroll
  for (int e = 0; e < 16; ++e) s += a[e];
  float q = s * s;
#pragma unroll
  for (int o = 32; o; o >>= 1) q += __shfl_xor(q, o, 64);
  if ((t & 63) == 0) r1[t >> 6] = q;
  __syncthreads();
  q = 0.f;
#pragma unroll
  for (int j = 0; j < 8; ++j) q += r1[j];
  float inv = 1.f / fmaxf(sqrtf(q), 1e-12f);
  unsigned short hv = f2bf(s * inv);
  mnbf[(size_t)i * DDIM + t] = hv;
  mnTbf[(size_t)t * MMEM + i] = hv;
}

// ---------------------------------------------------------------------------
// LayerNorm(len 300, eps=512) over (qkv_base + s4[row]*t2[col]); scatter q/k/v.
__global__ __launch_bounds__(256) void ln300_k(const float* __restrict__ x,
                                               const float* __restrict__ s4,
                                               const float* __restrict__ t2,
                                               const float* __restrict__ g,
                                               const float* __restrict__ bb,
                                               float* __restrict__ qm,
                                               float* __restrict__ km,
                                               float* __restrict__ vm) {
  __shared__ float r1[4], r2[4];
  int row = blockIdx.x, tid = threadIdx.x;
  const float* xr = x + (size_t)row * QKVW;
  const float s4r = s4[row];
  float v1 = xr[tid] + s4r * t2[tid];
  float v2 = (tid + 256 < QKVW) ? (xr[tid + 256] + s4r * t2[tid + 256]) : 0.f;
  float s = v1 + v2, q = v1 * v1 + v2 * v2;
#pragma unroll
  for (int o = 32; o; o >>= 1) { s += __shfl_xor(s, o, 64); q += __shfl_xor(q, o, 64); }
  if ((tid & 63) == 0) { r1[tid >> 6] = s; r2[tid >> 6] = q; }
  __syncthreads();
  s = r1[0] + r1[1] + r1[2] + r1[3];
  q = r2[0] + r2[1] + r2[2] + r2[3];
  float mean = s * (1.f / 300.f);
  float var = q * (1.f / 300.f) - mean * mean;
  float inv = rsqrtf(var + 512.0f);
  float y1 = (v1 - mean) * inv * g[tid] + bb[tid];
  int j = tid;
  if (j < 100)      qm[(size_t)j * DDIM + row] = y1;
  else if (j < 200) km[(size_t)(j - 100) * DDIM + row] = y1;
  else              vm[(size_t)(j - 200) * DDIM + row] = y1;
  if (tid + 256 < QKVW) {
    float y2 = (v2 - mean) * inv * g[tid + 256] + bb[tid + 256];
    vm[(size_t)(tid + 56) * DDIM + row] = y2;   // j2-200 = tid+56
  }
}

// ---------------------------------------------------------------------------
extern "C" void kernel_launch(void* const* d_in, const int* in_sizes, int n_in,
                              void* d_out, int out_size, void* d_ws, size_t ws_size,
                              hipStream_t stream) {
  (void)in_sizes; (void)n_in; (void)out_size; (void)ws_size;
  const float* fea    = (const float*)d_in[0];
  const float* item_w = (const float*)d_in[1];
  const float* rel_w  = (const float*)d_in[2];
  const float* W1     = (const float*)d_in[3];
  const float* b1     = (const float*)d_in[4];
  const float* W2     = (const float*)d_in[5];
  const float* b2     = (const float*)d_in[6];
  const float* W3     = (const float*)d_in[7];
  const float* b3     = (const float*)d_in[8];
  const float* Wqkv   = (const float*)d_in[9];
  const float* bqkv   = (const float*)d_in[10];
  const float* ln_g   = (const float*)d_in[11];
  const float* ln_b   = (const float*)d_in[12];
  const float* Wr1    = (const float*)d_in[13];
  const float* br1    = (const float*)d_in[14];
  float* out = (float*)d_out;
  float* ws = (float*)d_ws;

  // f32 region (S..item contiguous: zeroed by feat_cvtw blocks 741+)
  float* S       = ws;                         // 51,200
  float* ip4sum  = S       + 51200;            // 512
  float* ip2sum  = ip4sum  + 512;              // 512
  float* item    = ip2sum  + 512;              // 262,144
  float* qkv     = item    + 262144;           // 153,600
  float* qm      = qkv     + 153600;           // 51,200
  float* km      = qm      + 51200;            // 51,200
  float* vm      = km      + 51200;            // 51,200
  float* bcat    = vm      + 51200;            // 1,024
  float* t2      = bcat    + 1024;             // 300 (+pad)
  // u16 region
  unsigned short* u16base = (unsigned short*)(t2 + 512);
  unsigned short* partial = u16base;                 // 13,107,200 u16 (256 chunks)
  unsigned short* qnbf    = partial + 13107200;      // 8,388,608
  unsigned short* ip12bf  = qnbf    + 8388608;       // 16,777,216 (ld 1024)
  unsigned short* ip3bf   = ip12bf  + 16777216;      // 1,638,400 (ld 100)
  unsigned short* addrbf  = ip3bf   + 1638400;       // 2,097,152 (ld 128)
  unsigned short* relbf   = addrbf  + 2097152;       // 26,214,400
  unsigned short* mnbf    = relbf   + 26214400;      // 51,200
  unsigned short* mnTbf   = mnbf    + 51200;         // 51,200
  unsigned short* Wcat    = mnTbf   + 51200;         // 524,288
  unsigned short* W3bf    = Wcat    + 524288;        // 51,200
  unsigned short* Wqbf    = W3bf    + 51200;         // 153,600

  // 1) fused: fea copy + qnbf + weight cvt + zero atomic targets
  feat_cvtw_k<<<1048, 256, 0, stream>>>(fea, qnbf, out, W1, W2, W3, Wqkv,
                                        b1, b2, Wcat, W3bf, Wqbf, bcat, S);

  // 2) merged: ip12 GEMM || ip3 GEMM+softmax
  step2_k<<<1152, 256, 0, stream>>>(qnbf, Wcat, bcat, ip12bf, W3bf, b3, ip3bf);

  // 3) merged: item (symmetric, 10 tiles) || S || colsum(ip2)
  step3_k<<<832, 256, 0, stream>>>(ip12bf, ip3bf, item, S, ip2sum);

  // 4) merged: ip4sum || qkv_base GEMM || t2
  step4_k<<<813, 256, 0, stream>>>(S, rel_w, ip4sum, item, item_w,
                                   Wqbf, bqkv, qkv, ip2sum, Wqkv, t2);

  // 5) LN(eps=512) over qkv_base + s4*t2; split q/k/v
  ln300_k<<<512, 256, 0, stream>>>(qkv, ip4sum, t2, ln_g, ln_b, qm, km, vm);

  // 6) relbf = bf16(rel_w + einsum(tanh(q*k), v))
  rel0_mfma_k<<<dim3(4, MMEM), 256, 0, stream>>>(qm, km, vm, rel_w, relbf);

  // 7) memory = relbf @ Wr1 (bf16 partials); reduce + l2norm
  memgemm_k<<<dim3(MGCHUNK), 1024, 0, stream>>>(relbf, Wr1, partial);
  reduce_mn_k<<<MMEM, 512, 0, stream>>>(partial, br1, mnbf, mnTbf);

  // 8) addr = softmax(qnbf@mnTbf); mf = addrbf@mnbf -> out directly
  sm100_addr_k<<<128, 256, 0, stream>>>(qnbf, mnTbf, addrbf);
  gemm_mf_out_k<<<dim3(4, 128), 256, 0, stream>>>(addrbf, mnbf, out);
}

// Round 13
// 510.933 us; speedup vs baseline: 1.0615x; 1.0615x over previous
//
#include <hip/hip_runtime.h>
#include <hip/hip_bf16.h>

#define NTOK 16384
#define DDIM 512
#define MMEM 100
#define HWSZ 4096
#define QKVW 300

typedef __attribute__((ext_vector_type(8))) short short8v;   // 8 bf16
typedef __attribute__((ext_vector_type(4))) short short4v;   // 4 bf16
typedef __attribute__((ext_vector_type(4))) float f32x4;

__device__ __forceinline__ unsigned short f2bf(float x) {
  union { __hip_bfloat16 h; unsigned short u; } cv;
  cv.h = __float2bfloat16(x);
  return cv.u;
}
__device__ __forceinline__ float bf2f(unsigned short u) {
  union { unsigned int u; float f; } v; v.u = ((unsigned int)u) << 16;
  return v.f;
}

// ---------------------------------------------------------------------------
// feat + cvtw + zero merged. Blocks 0..511: fea read-once -> out copy + qnbf.
// Blocks 512..740: weights -> bf16. Blocks 741..1047: zero atomic targets.
__global__ __launch_bounds__(256) void feat_cvtw_k(
    const float* __restrict__ fea, unsigned short* __restrict__ qnbf,
    float* __restrict__ out,
    const float* __restrict__ W1, const float* __restrict__ W2,
    const float* __restrict__ W3, const float* __restrict__ Wq,
    const float* __restrict__ b1, const float* __restrict__ b2,
    unsigned short* __restrict__ Wcat, unsigned short* __restrict__ o3,
    unsigned short* __restrict__ oq, float* __restrict__ bcat,
    float* __restrict__ zbase) {
  if (blockIdx.x >= 741) {
    int zidx = (blockIdx.x - 741) * 256 + threadIdx.x;   // 78592 float4s
    if (zidx < 78592)
      ((float4*)zbase)[zidx] = make_float4(0.f, 0.f, 0.f, 0.f);
    return;
  }
  if (blockIdx.x >= 512) {
    int base = (blockIdx.x - 512) * 256 + threadIdx.x;
    for (int idx = base; idx < 467968; idx += 229 * 256) {
      if (idx < 262144) {
        int k = idx >> 9, n = idx & 511;
        Wcat[(size_t)k * 1024 + n] = f2bf(W1[idx]);
        Wcat[(size_t)k * 1024 + 512 + n] = f2bf(W2[idx]);
      } else if (idx < 313344) {
        o3[idx - 262144] = f2bf(W3[idx - 262144]);
      } else if (idx < 466944) {
        oq[idx - 313344] = f2bf(Wq[idx - 313344]);
      } else {
        int i = idx - 466944;
        bcat[i] = (i < 512) ? b1[i] : b2[i - 512];
      }
    }
    return;
  }
  __shared__ float tile[512][33];
  __shared__ float psum[8][32];
  __shared__ float invn_s[32];
  const int bid = blockIdx.x;                 // 512
  const int b = bid >> 7, hw0 = (bid & 127) * 32;
  const int t = threadIdx.x;
  const int hwo = t & 31, cg = t >> 5;
  const float* src = fea + (size_t)b * DDIM * HWSZ + hw0;
  float* dst = out + (size_t)b * (2 * DDIM) * HWSZ + hw0;
  float ss = 0.f;
#pragma unroll 8
  for (int i = 0; i < 64; ++i) {
    int c = cg * 64 + i;
    float v = src[(size_t)c * HWSZ + hwo];
    tile[c][hwo] = v;
    dst[(size_t)c * HWSZ + hwo] = v;
    ss += v * v;
  }
  psum[cg][hwo] = ss;
  __syncthreads();
  if (t < 32) {
    float s = 0.f;
#pragma unroll
    for (int j = 0; j < 8; ++j) s += psum[j][t];
    invn_s[t] = 1.f / fmaxf(sqrtf(s), 1e-12f);
  }
  __syncthreads();
  const int tok = t & 31, c0 = (t >> 5) * 64;
  const float inv = invn_s[tok];
  unsigned short* qp = qnbf + ((size_t)(b * HWSZ + hw0 + tok)) * DDIM + c0;
#pragma unroll
  for (int e8 = 0; e8 < 8; ++e8) {
    short8v p;
#pragma unroll
    for (int e = 0; e < 8; ++e)
      p[e] = (short)f2bf(tile[c0 + e8 * 8 + e][tok] * inv);
    *(short8v*)(qp + e8 * 8) = p;
  }
}

// ---------------------------------------------------------------------------
// Device body: bf16 MFMA GEMM tile (128x128), bf16 out. smem: As@0, Bs@10240.
__device__ __forceinline__ void gemm_body(
    char* smem, const unsigned short* __restrict__ A,
    const unsigned short* __restrict__ B, const float* __restrict__ bias,
    unsigned short* __restrict__ Cbf,
    int M, int N, int K, int lda, int ldb, int ldc, int bx, int by) {
  unsigned short (*As)[40] = (unsigned short(*)[40])smem;
  unsigned short (*Bs)[132] = (unsigned short(*)[132])(smem + 10240);
  const int tid = threadIdx.x;
  const int l = tid & 63, w = tid >> 6;
  const int l15 = l & 15, lhi = l >> 4;
  const int wm = w >> 1, wn = w & 1;
  const int row0 = by * 128, col0 = bx * 128;
  const int am = tid >> 1, akq = (tid & 1) << 4;
  const int bk = tid >> 3, bnq = (tid & 7) << 4;
  const int arow = row0 + am;
  f32x4 acc[4][4] = {};

  for (int k0 = 0; k0 < K; k0 += 32) {
    short8v av0 = {}, av1 = {}, bv0 = {}, bv1 = {};
    if (arow < M && k0 + akq < K) {
      const unsigned short* ap = A + (size_t)arow * lda + k0 + akq;
      if (k0 + akq + 15 < K) {
        av0 = *(const short8v*)ap;
        av1 = *(const short8v*)(ap + 8);
      } else {
#pragma unroll
        for (int e = 0; e < 8; ++e) {
          av0[e] = (k0 + akq + e < K) ? (short)ap[e] : (short)0;
          av1[e] = (k0 + akq + 8 + e < K) ? (short)ap[8 + e] : (short)0;
        }
      }
    }
    {
      const int kk = k0 + bk;
      if (kk < K) {
        const unsigned short* bp = B + (size_t)kk * ldb + col0 + bnq;
        if (col0 + bnq + 15 < N) {
          bv0 = *(const short8v*)bp;
          bv1 = *(const short8v*)(bp + 8);
        } else {
#pragma unroll
          for (int e = 0; e < 8; ++e) {
            bv0[e] = (col0 + bnq + e < N) ? (short)bp[e] : (short)0;
            bv1[e] = (col0 + bnq + 8 + e < N) ? (short)bp[8 + e] : (short)0;
          }
        }
      }
    }
    __syncthreads();
    *(short8v*)&As[am][akq] = av0;
    *(short8v*)&As[am][akq + 8] = av1;
    *(short8v*)&Bs[bk][bnq] = bv0;
    *(short8v*)&Bs[bk][bnq + 8] = bv1;
    __syncthreads();
    short8v af[4];
#pragma unroll
    for (int mt = 0; mt < 4; ++mt)
      af[mt] = *(const short8v*)&As[wm * 64 + mt * 16 + l15][lhi * 8];
#pragma unroll
    for (int ct = 0; ct < 4; ++ct) {
      union { short8v v; unsigned short u[8]; } bf;
      const int nn = wn * 64 + ct * 16 + l15;
#pragma unroll
      for (int j = 0; j < 8; ++j) bf.u[j] = Bs[lhi * 8 + j][nn];
#pragma unroll
      for (int mt = 0; mt < 4; ++mt)
        acc[mt][ct] = __builtin_amdgcn_mfma_f32_16x16x32_bf16(
            af[mt], bf.v, acc[mt][ct], 0, 0, 0);
    }
  }

#pragma unroll
  for (int mt = 0; mt < 4; ++mt) {
    const int rb = row0 + wm * 64 + mt * 16 + lhi * 4;
#pragma unroll
    for (int u = 0; u < 4; ++u) {
      const int r = rb + u;
      if (r >= M) continue;
#pragma unroll
      for (int ct = 0; ct < 4; ++ct) {
        const int c = col0 + wn * 64 + ct * 16 + l15;
        if (c >= N) continue;
        float val = acc[mt][ct][u];
        if (bias) val += bias[c];
        Cbf[(size_t)r * ldc + c] = f2bf(val);
      }
    }
  }
}

// Device body: N=100 GEMM (K=512) + fused row-softmax -> bf16 probs.
__device__ __forceinline__ void sm100_body(
    char* smem, const unsigned short* __restrict__ A,
    const unsigned short* __restrict__ B, const float* __restrict__ bias,
    unsigned short* __restrict__ obf, int lda, int ldb, int ldo, int rowblk) {
  unsigned short (*As)[40] = (unsigned short(*)[40])smem;
  unsigned short (*Bs)[132] = (unsigned short(*)[132])(smem + 10240);
  unsigned short (*Ps)[104] = (unsigned short(*)[104])smem;
  const int tid = threadIdx.x;
  const int l = tid & 63, w = tid >> 6;
  const int l15 = l & 15, lhi = l >> 4;
  const int wm = w >> 1, wn = w & 1;
  const int row0 = rowblk * 128;
  const int am = tid >> 1, akq = (tid & 1) << 4;
  const int bk = tid >> 3, bnq = (tid & 7) << 4;
  f32x4 acc[4][4] = {};

  for (int k0 = 0; k0 < DDIM; k0 += 32) {
    const unsigned short* ap = A + (size_t)(row0 + am) * lda + k0 + akq;
    short8v av0 = *(const short8v*)ap;
    short8v av1 = *(const short8v*)(ap + 8);
    short8v bv0 = {}, bv1 = {};
    const unsigned short* bp = B + (size_t)(k0 + bk) * ldb + bnq;
    if (bnq + 15 < MMEM) {
      bv0 = *(const short8v*)bp;
      bv1 = *(const short8v*)(bp + 8);
    } else {
#pragma unroll
      for (int e = 0; e < 8; ++e) {
        bv0[e] = (bnq + e < MMEM) ? (short)bp[e] : (short)0;
        bv1[e] = (bnq + 8 + e < MMEM) ? (short)bp[8 + e] : (short)0;
      }
    }
    __syncthreads();
    *(short8v*)&As[am][akq] = av0;
    *(short8v*)&As[am][akq + 8] = av1;
    *(short8v*)&Bs[bk][bnq] = bv0;
    *(short8v*)&Bs[bk][bnq + 8] = bv1;
    __syncthreads();
    short8v af[4];
#pragma unroll
    for (int mt = 0; mt < 4; ++mt)
      af[mt] = *(const short8v*)&As[wm * 64 + mt * 16 + l15][lhi * 8];
#pragma unroll
    for (int ct = 0; ct < 4; ++ct) {
      union { short8v v; unsigned short u[8]; } bf;
      const int nn = wn * 64 + ct * 16 + l15;
#pragma unroll
      for (int j = 0; j < 8; ++j) bf.u[j] = Bs[lhi * 8 + j][nn];
#pragma unroll
      for (int mt = 0; mt < 4; ++mt)
        acc[mt][ct] = __builtin_amdgcn_mfma_f32_16x16x32_bf16(
            af[mt], bf.v, acc[mt][ct], 0, 0, 0);
    }
  }

  __syncthreads();   // As/Bs dead; Ps overlays them
#pragma unroll
  for (int mt = 0; mt < 4; ++mt) {
#pragma unroll
    for (int u = 0; u < 4; ++u) {
      const int r = wm * 64 + mt * 16 + lhi * 4 + u;
#pragma unroll
      for (int ct = 0; ct < 4; ++ct) {
        const int c = wn * 64 + ct * 16 + l15;
        if (c < MMEM) {
          float val = acc[mt][ct][u];
          if (bias) val += bias[c];
          Ps[r][c] = f2bf(val);
        }
      }
    }
  }
  __syncthreads();
  for (int rr = 0; rr < 32; ++rr) {
    const int r = w * 32 + rr;
    float v0 = bf2f(Ps[r][l]);
    const bool has1 = (l + 64) < MMEM;
    float v1 = has1 ? bf2f(Ps[r][l + 64]) : -3.4e38f;
    float m = fmaxf(v0, v1);
#pragma unroll
    for (int o = 32; o; o >>= 1) m = fmaxf(m, __shfl_xor(m, o, 64));
    float e0 = expf(v0 - m);
    float e1 = has1 ? expf(v1 - m) : 0.f;
    float s = e0 + e1;
#pragma unroll
    for (int o = 32; o; o >>= 1) s += __shfl_xor(s, o, 64);
    float inv = 1.f / s;
    unsigned short* orow = obf + (size_t)(row0 + r) * ldo;
    orow[l] = f2bf(e0 * inv);
    if (has1) orow[l + 64] = f2bf(e1 * inv);
  }
}

// Device body: C(MxN) += A^T @ B over K-chunk (atomic f32 C).
__device__ __forceinline__ void atb_body(
    char* smem, const unsigned short* __restrict__ A,
    const unsigned short* __restrict__ B, float* __restrict__ C,
    int M, int N, int K, int lda, int ldb, int ldc, int KC,
    int bx, int by, int bz) {
  unsigned short (*As)[40] = (unsigned short(*)[40])smem;
  unsigned short (*Bs)[132] = (unsigned short(*)[132])(smem + 10240);
  const int tid = threadIdx.x;
  const int l = tid & 63, w = tid >> 6;
  const int l15 = l & 15, lhi = l >> 4;
  const int wm = w >> 1, wn = w & 1;
  const int row0 = by * 128, col0 = bx * 128;
  const int kbeg = bz * KC;
  const int kend = min(kbeg + KC, K);
  const int akk = tid >> 3, amq = (tid & 7) << 4;
  const int bk = tid >> 3, bnq = (tid & 7) << 4;
  f32x4 acc[4][4] = {};

  for (int k0 = kbeg; k0 < kend; k0 += 32) {
    unsigned short av[16]; short8v bv0 = {}, bv1 = {};
    {
      const int kk = k0 + akk;
      if (kk < kend) {
        const unsigned short* ap = A + (size_t)kk * lda + row0 + amq;
        if (row0 + amq + 15 < M) {
          *(short8v*)&av[0] = *(const short8v*)ap;
          *(short8v*)&av[8] = *(const short8v*)(ap + 8);
        } else {
#pragma unroll
          for (int e = 0; e < 16; ++e)
            av[e] = (row0 + amq + e < M) ? ap[e] : 0;
        }
      } else {
#pragma unroll
        for (int e = 0; e < 16; ++e) av[e] = 0;
      }
    }
    {
      const int kk = k0 + bk;
      if (kk < kend) {
        const unsigned short* bp = B + (size_t)kk * ldb + col0 + bnq;
        if (col0 + bnq + 15 < N) {
          bv0 = *(const short8v*)bp;
          bv1 = *(const short8v*)(bp + 8);
        } else {
#pragma unroll
          for (int e = 0; e < 8; ++e) {
            bv0[e] = (col0 + bnq + e < N) ? (short)bp[e] : (short)0;
            bv1[e] = (col0 + bnq + 8 + e < N) ? (short)bp[8 + e] : (short)0;
          }
        }
      }
    }
    __syncthreads();
#pragma unroll
    for (int e = 0; e < 16; ++e) As[amq + e][akk] = av[e];   // transposed
    *(short8v*)&Bs[bk][bnq] = bv0;
    *(short8v*)&Bs[bk][bnq + 8] = bv1;
    __syncthreads();
    short8v af[4];
#pragma unroll
    for (int mt = 0; mt < 4; ++mt)
      af[mt] = *(const short8v*)&As[wm * 64 + mt * 16 + l15][lhi * 8];
#pragma unroll
    for (int ct = 0; ct < 4; ++ct) {
      union { short8v v; unsigned short u[8]; } bf;
      const int nn = wn * 64 + ct * 16 + l15;
#pragma unroll
      for (int j = 0; j < 8; ++j) bf.u[j] = Bs[lhi * 8 + j][nn];
#pragma unroll
      for (int mt = 0; mt < 4; ++mt)
        acc[mt][ct] = __builtin_amdgcn_mfma_f32_16x16x32_bf16(
            af[mt], bf.v, acc[mt][ct], 0, 0, 0);
    }
  }

#pragma unroll
  for (int mt = 0; mt < 4; ++mt) {
    const int rb = row0 + wm * 64 + mt * 16 + lhi * 4;
#pragma unroll
    for (int u = 0; u < 4; ++u) {
      const int r = rb + u;
      if (r >= M) continue;
#pragma unroll
      for (int ct = 0; ct < 4; ++ct) {
        const int c = col0 + wn * 64 + ct * 16 + l15;
        if (c >= N) continue;
        atomicAdd(&C[(size_t)r * ldc + c], acc[mt][ct][u]);
      }
    }
  }
}

// ---------------------------------------------------------------------------
// step2: ip12 GEMM (blocks 0..1023) || ip3 GEMM+softmax (1024..1151)
__global__ __launch_bounds__(256) void step2_k(
    const unsigned short* __restrict__ qnbf, const unsigned short* __restrict__ Wcat,
    const float* __restrict__ bcat, unsigned short* __restrict__ ip12bf,
    const unsigned short* __restrict__ W3bf, const float* __restrict__ b3,
    unsigned short* __restrict__ ip3bf) {
  __shared__ char smem[26624];
  const int bid = blockIdx.x;
  if (bid < 1024) {
    gemm_body(smem, qnbf, Wcat, bcat, ip12bf, NTOK, 1024, DDIM,
              DDIM, 1024, 1024, bid & 7, bid >> 3);
  } else {
    sm100_body(smem, qnbf, W3bf, b3, ip3bf, DDIM, MMEM, MMEM, bid - 1024);
  }
}

// step3 (R11 form): atb_item (0..511) || atb_S (512..767) || colsum (768..1023)
__global__ __launch_bounds__(256) void step3_k(
    const unsigned short* __restrict__ ip12bf, const unsigned short* __restrict__ ip3bf,
    float* __restrict__ item, float* __restrict__ S, float* __restrict__ ip2sum) {
  __shared__ char smem[18688];
  const int bid = blockIdx.x;
  const int t = threadIdx.x;
  if (bid < 512) {
    atb_body(smem, ip12bf, ip12bf, item, DDIM, DDIM, NTOK,
             1024, 1024, DDIM, 512, bid & 3, (bid >> 2) & 3, bid >> 4);
  } else if (bid < 768) {
    const int b2 = bid - 512;
    atb_body(smem, ip3bf, ip12bf + 512, S, MMEM, DDIM, NTOK,
             MMEM, 1024, DDIM, 256, b2 & 3, 0, b2 >> 2);
  } else {
    const int cb = bid - 768;   // 0..255, 64 rows each
    const unsigned short* p = ip12bf + 512 + (size_t)cb * 64 * 1024 + t;
    float a0 = 0.f, a1 = 0.f, a2 = 0.f, a3 = 0.f;
    float b0 = 0.f, b1 = 0.f, b2 = 0.f, b3 = 0.f;
    for (int r = 0; r < 64; r += 4) {
      a0 += bf2f(p[(size_t)(r + 0) * 1024]); b0 += bf2f(p[(size_t)(r + 0) * 1024 + 256]);
      a1 += bf2f(p[(size_t)(r + 1) * 1024]); b1 += bf2f(p[(size_t)(r + 1) * 1024 + 256]);
      a2 += bf2f(p[(size_t)(r + 2) * 1024]); b2 += bf2f(p[(size_t)(r + 2) * 1024 + 256]);
      a3 += bf2f(p[(size_t)(r + 3) * 1024]); b3 += bf2f(p[(size_t)(r + 3) * 1024 + 256]);
    }
    atomicAdd(&ip2sum[t], (a0 + a1) + (a2 + a3));
    atomicAdd(&ip2sum[t + 256], (b0 + b1) + (b2 + b3));
  }
}

// ---------------------------------------------------------------------------
// step4: ip4sum (0..799) || qkv_base GEMM (800..811) || t2 = ip2sum^T @ Wqkv (812)
__global__ __launch_bounds__(256) void step4_k(
    const float* __restrict__ S, const float* __restrict__ rel_w,
    float* __restrict__ ip4sum,
    const float* __restrict__ item, const float* __restrict__ item_w,
    const unsigned short* __restrict__ Wqbf, const float* __restrict__ bqkv,
    float* __restrict__ qkv,
    const float* __restrict__ ip2sum, const float* __restrict__ Wqkv,
    float* __restrict__ t2) {
  __shared__ char smem[18688];
  const int bid = blockIdx.x;
  const int tid = threadIdx.x;
  if (bid < 800) {
    // ip4sum: 64 flat rows per block
    float* sv = (float*)smem;
    int r0 = bid * 64;
    if (tid < 64) sv[tid] = S[r0 + tid];
    __syncthreads();
    float a0 = 0.f, a1 = 0.f, a2 = 0.f, a3 = 0.f;
    float b0 = 0.f, b1 = 0.f, b2 = 0.f, b3 = 0.f;
    const float* base = rel_w + (size_t)r0 * DDIM;
    for (int r = 0; r < 64; r += 4) {
      const float* p0 = base + (size_t)(r + 0) * DDIM;
      const float* p1 = base + (size_t)(r + 1) * DDIM;
      const float* p2 = base + (size_t)(r + 2) * DDIM;
      const float* p3 = base + (size_t)(r + 3) * DDIM;
      a0 = fmaf(sv[r + 0], p0[tid], a0); b0 = fmaf(sv[r + 0], p0[tid + 256], b0);
      a1 = fmaf(sv[r + 1], p1[tid], a1); b1 = fmaf(sv[r + 1], p1[tid + 256], b1);
      a2 = fmaf(sv[r + 2], p2[tid], a2); b2 = fmaf(sv[r + 2], p2[tid + 256], b2);
      a3 = fmaf(sv[r + 3], p3[tid], a3); b3 = fmaf(sv[r + 3], p3[tid + 256], b3);
    }
    atomicAdd(&ip4sum[tid], (a0 + a1) + (a2 + a3));
    atomicAdd(&ip4sum[tid + 256], (b0 + b1) + (b2 + b3));
    return;
  }
  if (bid == 812) {
    // t2[n] = sum_d ip2sum[d] * Wqkv[d, n]   (f32, tiny)
    for (int n = tid; n < QKVW; n += 256) {
      float s = 0.f;
      for (int d = 0; d < DDIM; ++d) s = fmaf(ip2sum[d], Wqkv[(size_t)d * QKVW + n], s);
      t2[n] = s;
    }
    return;
  }
  // qkv_base = (item + item_w) @ Wqbf + bqkv  (rank-1 term folded into ln300)
  {
    unsigned short (*As)[40] = (unsigned short(*)[40])smem;
    unsigned short (*Bs)[132] = (unsigned short(*)[132])(smem + 10240);
    const int qb = bid - 800;                 // 0..11
    const int bx = qb % 3, by = qb / 3;
    const int l = tid & 63, w = tid >> 6;
    const int l15 = l & 15, lhi = l >> 4;
    const int wm = w >> 1, wn = w & 1;
    const int row0 = by * 128, col0 = bx * 128;
    const int am = tid >> 1, akq = (tid & 1) << 4;
    const int bk = tid >> 3, bnq = (tid & 7) << 4;
    const int arow = row0 + am;
    f32x4 acc[4][4] = {};

    for (int k0 = 0; k0 < DDIM; k0 += 32) {
      float av[16];
      {
        const size_t off = (size_t)arow * DDIM + k0 + akq;
#pragma unroll
        for (int u = 0; u < 4; ++u) {
          float4 a = *(const float4*)(item + off + 4 * u);
          float4 b = *(const float4*)(item_w + off + 4 * u);
          av[4*u+0] = a.x + b.x;
          av[4*u+1] = a.y + b.y;
          av[4*u+2] = a.z + b.z;
          av[4*u+3] = a.w + b.w;
        }
      }
      short8v bv0 = {}, bv1 = {};
      {
        const int kk = k0 + bk;
        const unsigned short* bp = Wqbf + (size_t)kk * QKVW + col0 + bnq;
        if (col0 + bnq + 15 < QKVW) {
          bv0 = *(const short8v*)bp;
          bv1 = *(const short8v*)(bp + 8);
        } else {
#pragma unroll
          for (int e = 0; e < 8; ++e) {
            bv0[e] = (col0 + bnq + e < QKVW) ? (short)bp[e] : (short)0;
            bv1[e] = (col0 + bnq + 8 + e < QKVW) ? (short)bp[8 + e] : (short)0;
          }
        }
      }
      __syncthreads();
      {
        short8v p0, p1;
#pragma unroll
        for (int e = 0; e < 8; ++e) p0[e] = (short)f2bf(av[e]);
#pragma unroll
        for (int e = 0; e < 8; ++e) p1[e] = (short)f2bf(av[8 + e]);
        *(short8v*)&As[am][akq] = p0;
        *(short8v*)&As[am][akq + 8] = p1;
      }
      *(short8v*)&Bs[bk][bnq] = bv0;
      *(short8v*)&Bs[bk][bnq + 8] = bv1;
      __syncthreads();
      short8v af[4];
#pragma unroll
      for (int mt = 0; mt < 4; ++mt)
        af[mt] = *(const short8v*)&As[wm * 64 + mt * 16 + l15][lhi * 8];
#pragma unroll
      for (int ct = 0; ct < 4; ++ct) {
        union { short8v v; unsigned short u[8]; } bf;
        const int nn = wn * 64 + ct * 16 + l15;
#pragma unroll
        for (int j = 0; j < 8; ++j) bf.u[j] = Bs[lhi * 8 + j][nn];
#pragma unroll
        for (int mt = 0; mt < 4; ++mt)
          acc[mt][ct] = __builtin_amdgcn_mfma_f32_16x16x32_bf16(
              af[mt], bf.v, acc[mt][ct], 0, 0, 0);
      }
    }

#pragma unroll
    for (int mt = 0; mt < 4; ++mt) {
      const int rb = row0 + wm * 64 + mt * 16 + lhi * 4;
#pragma unroll
      for (int u = 0; u < 4; ++u) {
        const int r = rb + u;
#pragma unroll
        for (int ct = 0; ct < 4; ++ct) {
          const int c = col0 + wn * 64 + ct * 16 + l15;
          if (c >= QKVW) continue;
          qkv[(size_t)r * QKVW + c] = acc[mt][ct][u] + bqkv[c];
        }
      }
    }
  }
}

// addr GEMM + softmax (standalone)
__global__ __launch_bounds__(256) void sm100_addr_k(
    const unsigned short* __restrict__ qnbf, const unsigned short* __restrict__ mnTbf,
    unsigned short* __restrict__ addrbf) {
  __shared__ char smem[26624];
  sm100_body(smem, qnbf, mnTbf, nullptr, addrbf, DDIM, MMEM, 128, blockIdx.x);
}

// ---------------------------------------------------------------------------
// mf GEMM writing out directly (channel-major) via LDS bf16 transpose epilogue.
__global__ __launch_bounds__(256) void gemm_mf_out_k(
    const unsigned short* __restrict__ A, const unsigned short* __restrict__ B,
    float* __restrict__ out) {
  __shared__ char smem[35328];
  unsigned short (*As)[40] = (unsigned short(*)[40])smem;
  unsigned short (*Bs)[132] = (unsigned short(*)[132])(smem + 10240);
  unsigned short (*Ps)[138] = (unsigned short(*)[138])smem;  // overlay after loop
  const int tid = threadIdx.x;
  const int l = tid & 63, w = tid >> 6;
  const int l15 = l & 15, lhi = l >> 4;
  const int wm = w >> 1, wn = w & 1;
  const int row0 = blockIdx.y * 128, col0 = blockIdx.x * 128;
  const int am = tid >> 1, akq = (tid & 1) << 4;
  const int bk = tid >> 3, bnq = (tid & 7) << 4;
  const int K = MMEM, lda = 128, ldb = DDIM;
  f32x4 acc[4][4] = {};

  for (int k0 = 0; k0 < 128; k0 += 32) {
    short8v av0 = {}, av1 = {}, bv0 = {}, bv1 = {};
    if (k0 + akq < K) {
      const unsigned short* ap = A + (size_t)(row0 + am) * lda + k0 + akq;
      if (k0 + akq + 15 < K) {
        av0 = *(const short8v*)ap;
        av1 = *(const short8v*)(ap + 8);
      } else {
#pragma unroll
        for (int e = 0; e < 8; ++e) {
          av0[e] = (k0 + akq + e < K) ? (short)ap[e] : (short)0;
          av1[e] = (k0 + akq + 8 + e < K) ? (short)ap[8 + e] : (short)0;
        }
      }
    }
    {
      const int kk = k0 + bk;
      if (kk < K) {
        const unsigned short* bp = B + (size_t)kk * ldb + col0 + bnq;
        bv0 = *(const short8v*)bp;
        bv1 = *(const short8v*)(bp + 8);
      }
    }
    __syncthreads();
    *(short8v*)&As[am][akq] = av0;
    *(short8v*)&As[am][akq + 8] = av1;
    *(short8v*)&Bs[bk][bnq] = bv0;
    *(short8v*)&Bs[bk][bnq + 8] = bv1;
    __syncthreads();
    short8v af[4];
#pragma unroll
    for (int mt = 0; mt < 4; ++mt)
      af[mt] = *(const short8v*)&As[wm * 64 + mt * 16 + l15][lhi * 8];
#pragma unroll
    for (int ct = 0; ct < 4; ++ct) {
      union { short8v v; unsigned short u[8]; } bf;
      const int nn = wn * 64 + ct * 16 + l15;
#pragma unroll
      for (int j = 0; j < 8; ++j) bf.u[j] = Bs[lhi * 8 + j][nn];
#pragma unroll
      for (int mt = 0; mt < 4; ++mt)
        acc[mt][ct] = __builtin_amdgcn_mfma_f32_16x16x32_bf16(
            af[mt], bf.v, acc[mt][ct], 0, 0, 0);
    }
  }

  __syncthreads();   // As/Bs dead; Ps overlays
#pragma unroll
  for (int mt = 0; mt < 4; ++mt) {
#pragma unroll
    for (int u = 0; u < 4; ++u) {
      const int r = wm * 64 + mt * 16 + lhi * 4 + u;   // hw within tile
#pragma unroll
      for (int ct = 0; ct < 4; ++ct) {
        const int c = wn * 64 + ct * 16 + l15;          // channel within tile
        Ps[r][c] = f2bf(acc[mt][ct][u]);
      }
    }
  }
  __syncthreads();
  const int b = row0 >> 12;
  const int hwb = row0 & 4095;
  const int j = tid & 63;
  float* obase = out + (size_t)b * 4194304 + (size_t)(512 + col0) * HWSZ + hwb;
  for (int cr = tid >> 6; cr < 128; cr += 4) {
    obase[(size_t)cr * HWSZ + j]      = bf2f(Ps[j][cr]);
    obase[(size_t)cr * HWSZ + j + 64] = bf2f(Ps[j + 64][cr]);
  }
}

// ---------------------------------------------------------------------------
// rel0 via MFMA (known-good)
__global__ __launch_bounds__(256) void rel0_mfma_k(
    const float* __restrict__ qm, const float* __restrict__ km,
    const float* __restrict__ vm, const float* __restrict__ rel_w,
    unsigned short* __restrict__ relbf) {
  __shared__ unsigned short Ts[128][136];
  __shared__ unsigned short Vs[128][136];
  __shared__ float qv[128];
  const int i = blockIdx.y;
  const int d0 = blockIdx.x * 128;
  const int tid = threadIdx.x;
  const int l = tid & 63, w = tid >> 6;
  const int l15 = l & 15, lhi = l >> 4;
  const int wm = w >> 1, wn = w & 1;

  if (tid < 128) qv[tid] = qm[(size_t)i * DDIM + d0 + tid];
  __syncthreads();
#pragma unroll
  for (int p = 0; p < 8; ++p) {
    int g = p * 2048 + tid * 8;
    int j = g >> 7, dd = g & 127;
    if (j < MMEM) {
      const float* kp = km + (size_t)j * DDIM + d0 + dd;
      float4 k0v = *(const float4*)kp;
      float4 k1v = *(const float4*)(kp + 4);
      float kv[8] = {k0v.x, k0v.y, k0v.z, k0v.w, k1v.x, k1v.y, k1v.z, k1v.w};
#pragma unroll
      for (int e = 0; e < 8; ++e)
        Ts[dd + e][j] = f2bf(tanhf(qv[dd + e] * kv[e]));
    } else {
#pragma unroll
      for (int e = 0; e < 8; ++e) Ts[dd + e][j] = 0;
    }
  }

  for (int f0 = 0; f0 < DDIM; f0 += 128) {
    __syncthreads();
#pragma unroll
    for (int p = 0; p < 8; ++p) {
      int g = p * 2048 + tid * 8;
      int j = g >> 7, ff = g & 127;
      short8v pv;
      if (j < MMEM) {
        const float* vp = vm + (size_t)j * DDIM + f0 + ff;
        float4 v0 = *(const float4*)vp;
        float4 v1 = *(const float4*)(vp + 4);
        pv[0] = (short)f2bf(v0.x); pv[1] = (short)f2bf(v0.y);
        pv[2] = (short)f2bf(v0.z); pv[3] = (short)f2bf(v0.w);
        pv[4] = (short)f2bf(v1.x); pv[5] = (short)f2bf(v1.y);
        pv[6] = (short)f2bf(v1.z); pv[7] = (short)f2bf(v1.w);
      } else {
#pragma unroll
        for (int e = 0; e < 8; ++e) pv[e] = 0;
      }
      *(short8v*)&Vs[j][ff] = pv;
    }
    __syncthreads();
    f32x4 acc[4][4] = {};
#pragma unroll
    for (int ks = 0; ks < 4; ++ks) {
      const int kb = ks * 32;
      short8v af[4];
#pragma unroll
      for (int mt = 0; mt < 4; ++mt)
        af[mt] = *(const short8v*)&Ts[wm * 64 + mt * 16 + l15][kb + lhi * 8];
#pragma unroll
      for (int ct = 0; ct < 4; ++ct) {
        union { short8v v; unsigned short u[8]; } bf;
        const int nn = wn * 64 + ct * 16 + l15;
#pragma unroll
        for (int jj = 0; jj < 8; ++jj) bf.u[jj] = Vs[kb + lhi * 8 + jj][nn];
#pragma unroll
        for (int mt = 0; mt < 4; ++mt)
          acc[mt][ct] = __builtin_amdgcn_mfma_f32_16x16x32_bf16(
              af[mt], bf.v, acc[mt][ct], 0, 0, 0);
      }
    }
#pragma unroll
    for (int mt = 0; mt < 4; ++mt) {
#pragma unroll
      for (int u = 0; u < 4; ++u) {
        const int d = d0 + wm * 64 + mt * 16 + lhi * 4 + u;
        const size_t base = (size_t)i * 262144 + (size_t)d * DDIM;
#pragma unroll
        for (int ct = 0; ct < 4; ++ct) {
          const int f = f0 + wn * 64 + ct * 16 + l15;
          relbf[base + f] = f2bf(rel_w[base + f] + acc[mt][ct][u]);
        }
      }
    }
  }
}

// ---------------------------------------------------------------------------
// memgemm: 1024 threads (16 waves), KC=1024, 256 chunks, bf16 partials.
#define MGK 262144
#define MGKC 1024
#define MGCHUNK 256
__global__ __launch_bounds__(1024, 4) void memgemm_k(
    const unsigned short* __restrict__ Ag, const float* __restrict__ Bg,
    unsigned short* __restrict__ partial) {
  __shared__ unsigned short As[128][44];
  __shared__ unsigned short Bs[32][520];
  const int tid = threadIdx.x;
  const int l = tid & 63, w = tid >> 6;
  const int l15 = l & 15, lhi = l >> 4;
  const int kbeg = blockIdx.x * MGKC;
  const int arow = tid >> 3, akq = tid & 7;
  const int bk = tid >> 5, bnq = (tid & 31) * 16;
  const int bsw = ((bk >> 3) & 3) << 4;
  const int csw = lhi << 4;
  f32x4 acc[8][2] = {};

  for (int t32 = 0; t32 < MGKC / 32; ++t32) {
    const int kb = kbeg + t32 * 32;
    short4v av = {};
    if (arow < MMEM)
      av = *(const short4v*)(Ag + (size_t)arow * MGK + kb + akq * 4);
    float4 bv[4];
    const float* bp = Bg + (size_t)(kb + bk) * DDIM + bnq;
#pragma unroll
    for (int u = 0; u < 4; ++u) bv[u] = *(const float4*)(bp + 4 * u);
    __syncthreads();
    *(short4v*)&As[arow][akq * 4] = av;
#pragma unroll
    for (int u = 0; u < 2; ++u) {
      short8v pb;
      pb[0] = (short)f2bf(bv[2*u].x);   pb[1] = (short)f2bf(bv[2*u].y);
      pb[2] = (short)f2bf(bv[2*u].z);   pb[3] = (short)f2bf(bv[2*u].w);
      pb[4] = (short)f2bf(bv[2*u+1].x); pb[5] = (short)f2bf(bv[2*u+1].y);
      pb[6] = (short)f2bf(bv[2*u+1].z); pb[7] = (short)f2bf(bv[2*u+1].w);
      *(short8v*)&Bs[bk][(bnq + u * 8) ^ bsw] = pb;
    }
    __syncthreads();
    union { short8v v; unsigned short u[8]; } bf0, bf1;
    const int nn0 = w * 32 + l15, nn1 = w * 32 + 16 + l15;
#pragma unroll
    for (int j = 0; j < 8; ++j) {
      bf0.u[j] = Bs[lhi * 8 + j][nn0 ^ csw];
      bf1.u[j] = Bs[lhi * 8 + j][nn1 ^ csw];
    }
#pragma unroll
    for (int mt = 0; mt < 8; ++mt) {
      short8v af = *(const short8v*)&As[mt * 16 + l15][lhi * 8];
      acc[mt][0] = __builtin_amdgcn_mfma_f32_16x16x32_bf16(af, bf0.v, acc[mt][0], 0, 0, 0);
      acc[mt][1] = __builtin_amdgcn_mfma_f32_16x16x32_bf16(af, bf1.v, acc[mt][1], 0, 0, 0);
    }
  }

  unsigned short* pw = partial + (size_t)blockIdx.x * (MMEM * DDIM);
#pragma unroll
  for (int mt = 0; mt < 8; ++mt) {
    const int r0 = mt * 16 + lhi * 4;
#pragma unroll
    for (int r = 0; r < 4; ++r) {
      const int row = r0 + r;
      if (row < MMEM) {
        pw[(size_t)row * DDIM + w * 32 + l15]      = f2bf(acc[mt][0][r]);
        pw[(size_t)row * DDIM + w * 32 + 16 + l15] = f2bf(acc[mt][1][r]);
      }
    }
  }
}

// Fused reduce(256 bf16 partials) + br1 + l2norm -> mnbf/mnTbf (16 accumulators).
__global__ __launch_bounds__(512) void reduce_mn_k(
    const unsigned short* __restrict__ partial, const float* __restrict__ br1,
    unsigned short* __restrict__ mnbf, unsigned short* __restrict__ mnTbf) {
  __shared__ float r1[8];
  const int i = blockIdx.x, t = threadIdx.x;
  const unsigned short* p = partial + (size_t)i * DDIM + t;
  float a[16] = {};
  const size_t zs = (size_t)(MMEM * DDIM);
  for (int z = 0; z < MGCHUNK; z += 16) {
#pragma unroll
    for (int e = 0; e < 16; ++e) a[e] += bf2f(p[(z + e) * zs]);
  }
  float s = br1[t];
#pragma unroll
  for (int e = 0; e < 16; ++e) s += a[e];
  float q = s * s;
#pragma unroll
  for (int o = 32; o; o >>= 1) q += __shfl_xor(q, o, 64);
  if ((t & 63) == 0) r1[t >> 6] = q;
  __syncthreads();
  q = 0.f;
#pragma unroll
  for (int j = 0; j < 8; ++j) q += r1[j];
  float inv = 1.f / fmaxf(sqrtf(q), 1e-12f);
  unsigned short hv = f2bf(s * inv);
  mnbf[(size_t)i * DDIM + t] = hv;
  mnTbf[(size_t)t * MMEM + i] = hv;
}

// ---------------------------------------------------------------------------
// LayerNorm(len 300, eps=512) over (qkv_base + s4[row]*t2[col]); scatter q/k/v.
__global__ __launch_bounds__(256) void ln300_k(const float* __restrict__ x,
                                               const float* __restrict__ s4,
                                               const float* __restrict__ t2,
                                               const float* __restrict__ g,
                                               const float* __restrict__ bb,
                                               float* __restrict__ qm,
                                               float* __restrict__ km,
                                               float* __restrict__ vm) {
  __shared__ float r1[4], r2[4];
  int row = blockIdx.x, tid = threadIdx.x;
  const float* xr = x + (size_t)row * QKVW;
  const float s4r = s4[row];
  float v1 = xr[tid] + s4r * t2[tid];
  float v2 = (tid + 256 < QKVW) ? (xr[tid + 256] + s4r * t2[tid + 256]) : 0.f;
  float s = v1 + v2, q = v1 * v1 + v2 * v2;
#pragma unroll
  for (int o = 32; o; o >>= 1) { s += __shfl_xor(s, o, 64); q += __shfl_xor(q, o, 64); }
  if ((tid & 63) == 0) { r1[tid >> 6] = s; r2[tid >> 6] = q; }
  __syncthreads();
  s = r1[0] + r1[1] + r1[2] + r1[3];
  q = r2[0] + r2[1] + r2[2] + r2[3];
  float mean = s * (1.f / 300.f);
  float var = q * (1.f / 300.f) - mean * mean;
  float inv = rsqrtf(var + 512.0f);
  float y1 = (v1 - mean) * inv * g[tid] + bb[tid];
  int j = tid;
  if (j < 100)      qm[(size_t)j * DDIM + row] = y1;
  else if (j < 200) km[(size_t)(j - 100) * DDIM + row] = y1;
  else              vm[(size_t)(j - 200) * DDIM + row] = y1;
  if (tid + 256 < QKVW) {
    float y2 = (v2 - mean) * inv * g[tid + 256] + bb[tid + 256];
    vm[(size_t)(tid + 56) * DDIM + row] = y2;   // j2-200 = tid+56
  }
}

// ---------------------------------------------------------------------------
extern "C" void kernel_launch(void* const* d_in, const int* in_sizes, int n_in,
                              void* d_out, int out_size, void* d_ws, size_t ws_size,
                              hipStream_t stream) {
  (void)in_sizes; (void)n_in; (void)out_size; (void)ws_size;
  const float* fea    = (const float*)d_in[0];
  const float* item_w = (const float*)d_in[1];
  const float* rel_w  = (const float*)d_in[2];
  const float* W1     = (const float*)d_in[3];
  const float* b1     = (const float*)d_in[4];
  const float* W2     = (const float*)d_in[5];
  const float* b2     = (const float*)d_in[6];
  const float* W3     = (const float*)d_in[7];
  const float* b3     = (const float*)d_in[8];
  const float* Wqkv   = (const float*)d_in[9];
  const float* bqkv   = (const float*)d_in[10];
  const float* ln_g   = (const float*)d_in[11];
  const float* ln_b   = (const float*)d_in[12];
  const float* Wr1    = (const float*)d_in[13];
  const float* br1    = (const float*)d_in[14];
  float* out = (float*)d_out;
  float* ws = (float*)d_ws;

  // f32 region (S..item contiguous: zeroed by feat_cvtw blocks 741+)
  float* S       = ws;                         // 51,200
  float* ip4sum  = S       + 51200;            // 512
  float* ip2sum  = ip4sum  + 512;              // 512
  float* item    = ip2sum  + 512;              // 262,144
  float* qkv     = item    + 262144;           // 153,600
  float* qm      = qkv     + 153600;           // 51,200
  float* km      = qm      + 51200;            // 51,200
  float* vm      = km      + 51200;            // 51,200
  float* bcat    = vm      + 51200;            // 1,024
  float* t2      = bcat    + 1024;             // 300 (+pad)
  // u16 region
  unsigned short* u16base = (unsigned short*)(t2 + 512);
  unsigned short* partial = u16base;                 // 13,107,200 u16 (256 chunks)
  unsigned short* qnbf    = partial + 13107200;      // 8,388,608
  unsigned short* ip12bf  = qnbf    + 8388608;       // 16,777,216 (ld 1024)
  unsigned short* ip3bf   = ip12bf  + 16777216;      // 1,638,400 (ld 100)
  unsigned short* addrbf  = ip3bf   + 1638400;       // 2,097,152 (ld 128)
  unsigned short* relbf   = addrbf  + 2097152;       // 26,214,400
  unsigned short* mnbf    = relbf   + 26214400;      // 51,200
  unsigned short* mnTbf   = mnbf    + 51200;         // 51,200
  unsigned short* Wcat    = mnTbf   + 51200;         // 524,288
  unsigned short* W3bf    = Wcat    + 524288;        // 51,200
  unsigned short* Wqbf    = W3bf    + 51200;         // 153,600

  // 1) fused: fea copy + qnbf + weight cvt + zero atomic targets
  feat_cvtw_k<<<1048, 256, 0, stream>>>(fea, qnbf, out, W1, W2, W3, Wqkv,
                                        b1, b2, Wcat, W3bf, Wqbf, bcat, S);

  // 2) merged: ip12 GEMM || ip3 GEMM+softmax
  step2_k<<<1152, 256, 0, stream>>>(qnbf, Wcat, bcat, ip12bf, W3bf, b3, ip3bf);

  // 3) merged (R11 form): item || S || colsum(ip2)
  step3_k<<<1024, 256, 0, stream>>>(ip12bf, ip3bf, item, S, ip2sum);

  // 4) merged: ip4sum || qkv_base GEMM || t2
  step4_k<<<813, 256, 0, stream>>>(S, rel_w, ip4sum, item, item_w,
                                   Wqbf, bqkv, qkv, ip2sum, Wqkv, t2);

  // 5) LN(eps=512) over qkv_base + s4*t2; split q/k/v
  ln300_k<<<512, 256, 0, stream>>>(qkv, ip4sum, t2, ln_g, ln_b, qm, km, vm);

  // 6) relbf = bf16(rel_w + einsum(tanh(q*k), v))
  rel0_mfma_k<<<dim3(4, MMEM), 256, 0, stream>>>(qm, km, vm, rel_w, relbf);

  // 7) memory = relbf @ Wr1 (bf16 partials); reduce + l2norm
  memgemm_k<<<dim3(MGCHUNK), 1024, 0, stream>>>(relbf, Wr1, partial);
  reduce_mn_k<<<MMEM, 512, 0, stream>>>(partial, br1, mnbf, mnTbf);

  // 8) addr = softmax(qnbf@mnTbf); mf = addrbf@mnbf -> out directly
  sm100_addr_k<<<128, 256, 0, stream>>>(qnbf, mnTbf, addrbf);
  gemm_mf_out_k<<<dim3(4, 128), 256, 0, stream>>>(addrbf, mnbf, out);
}

// Round 14
// 483.044 us; speedup vs baseline: 1.1228x; 1.0577x over previous
//
#include <hip/hip_runtime.h>
#include <hip/hip_bf16.h>

#define NTOK 16384
#define DDIM 512
#define MMEM 100
#define HWSZ 4096
#define QKVW 300

typedef __attribute__((ext_vector_type(8))) short short8v;   // 8 bf16
typedef __attribute__((ext_vector_type(4))) short short4v;   // 4 bf16
typedef __attribute__((ext_vector_type(4))) float f32x4;

__device__ __forceinline__ unsigned short f2bf(float x) {
  union { __hip_bfloat16 h; unsigned short u; } cv;
  cv.h = __float2bfloat16(x);
  return cv.u;
}
__device__ __forceinline__ float bf2f(unsigned short u) {
  union { unsigned int u; float f; } v; v.u = ((unsigned int)u) << 16;
  return v.f;
}

// ---------------------------------------------------------------------------
// feat + cvtw + zero merged. Blocks 0..511: fea read-once -> out copy + qnbf.
// Blocks 512..740: weights -> bf16. Blocks 741..1047: zero atomic targets.
__global__ __launch_bounds__(256) void feat_cvtw_k(
    const float* __restrict__ fea, unsigned short* __restrict__ qnbf,
    float* __restrict__ out,
    const float* __restrict__ W1, const float* __restrict__ W2,
    const float* __restrict__ W3, const float* __restrict__ Wq,
    const float* __restrict__ b1, const float* __restrict__ b2,
    unsigned short* __restrict__ Wcat, unsigned short* __restrict__ o3,
    unsigned short* __restrict__ oq, float* __restrict__ bcat,
    float* __restrict__ zbase) {
  if (blockIdx.x >= 741) {
    int zidx = (blockIdx.x - 741) * 256 + threadIdx.x;   // 78592 float4s
    if (zidx < 78592)
      ((float4*)zbase)[zidx] = make_float4(0.f, 0.f, 0.f, 0.f);
    return;
  }
  if (blockIdx.x >= 512) {
    int base = (blockIdx.x - 512) * 256 + threadIdx.x;
    for (int idx = base; idx < 467968; idx += 229 * 256) {
      if (idx < 262144) {
        int k = idx >> 9, n = idx & 511;
        Wcat[(size_t)k * 1024 + n] = f2bf(W1[idx]);
        Wcat[(size_t)k * 1024 + 512 + n] = f2bf(W2[idx]);
      } else if (idx < 313344) {
        o3[idx - 262144] = f2bf(W3[idx - 262144]);
      } else if (idx < 466944) {
        oq[idx - 313344] = f2bf(Wq[idx - 313344]);
      } else {
        int i = idx - 466944;
        bcat[i] = (i < 512) ? b1[i] : b2[i - 512];
      }
    }
    return;
  }
  __shared__ float tile[512][33];
  __shared__ float psum[8][32];
  __shared__ float invn_s[32];
  const int bid = blockIdx.x;                 // 512
  const int b = bid >> 7, hw0 = (bid & 127) * 32;
  const int t = threadIdx.x;
  const int hwo = t & 31, cg = t >> 5;
  const float* src = fea + (size_t)b * DDIM * HWSZ + hw0;
  float* dst = out + (size_t)b * (2 * DDIM) * HWSZ + hw0;
  float ss = 0.f;
#pragma unroll 8
  for (int i = 0; i < 64; ++i) {
    int c = cg * 64 + i;
    float v = src[(size_t)c * HWSZ + hwo];
    tile[c][hwo] = v;
    dst[(size_t)c * HWSZ + hwo] = v;
    ss += v * v;
  }
  psum[cg][hwo] = ss;
  __syncthreads();
  if (t < 32) {
    float s = 0.f;
#pragma unroll
    for (int j = 0; j < 8; ++j) s += psum[j][t];
    invn_s[t] = 1.f / fmaxf(sqrtf(s), 1e-12f);
  }
  __syncthreads();
  const int tok = t & 31, c0 = (t >> 5) * 64;
  const float inv = invn_s[tok];
  unsigned short* qp = qnbf + ((size_t)(b * HWSZ + hw0 + tok)) * DDIM + c0;
#pragma unroll
  for (int e8 = 0; e8 < 8; ++e8) {
    short8v p;
#pragma unroll
    for (int e = 0; e < 8; ++e)
      p[e] = (short)f2bf(tile[c0 + e8 * 8 + e][tok] * inv);
    *(short8v*)(qp + e8 * 8) = p;
  }
}

// ---------------------------------------------------------------------------
// Device body: bf16 MFMA GEMM tile (128x128), bf16 out. smem: As@0, Bs@10240.
__device__ __forceinline__ void gemm_body(
    char* smem, const unsigned short* __restrict__ A,
    const unsigned short* __restrict__ B, const float* __restrict__ bias,
    unsigned short* __restrict__ Cbf,
    int M, int N, int K, int lda, int ldb, int ldc, int bx, int by) {
  unsigned short (*As)[40] = (unsigned short(*)[40])smem;
  unsigned short (*Bs)[132] = (unsigned short(*)[132])(smem + 10240);
  const int tid = threadIdx.x;
  const int l = tid & 63, w = tid >> 6;
  const int l15 = l & 15, lhi = l >> 4;
  const int wm = w >> 1, wn = w & 1;
  const int row0 = by * 128, col0 = bx * 128;
  const int am = tid >> 1, akq = (tid & 1) << 4;
  const int bk = tid >> 3, bnq = (tid & 7) << 4;
  const int arow = row0 + am;
  f32x4 acc[4][4] = {};

  for (int k0 = 0; k0 < K; k0 += 32) {
    short8v av0 = {}, av1 = {}, bv0 = {}, bv1 = {};
    if (arow < M && k0 + akq < K) {
      const unsigned short* ap = A + (size_t)arow * lda + k0 + akq;
      if (k0 + akq + 15 < K) {
        av0 = *(const short8v*)ap;
        av1 = *(const short8v*)(ap + 8);
      } else {
#pragma unroll
        for (int e = 0; e < 8; ++e) {
          av0[e] = (k0 + akq + e < K) ? (short)ap[e] : (short)0;
          av1[e] = (k0 + akq + 8 + e < K) ? (short)ap[8 + e] : (short)0;
        }
      }
    }
    {
      const int kk = k0 + bk;
      if (kk < K) {
        const unsigned short* bp = B + (size_t)kk * ldb + col0 + bnq;
        if (col0 + bnq + 15 < N) {
          bv0 = *(const short8v*)bp;
          bv1 = *(const short8v*)(bp + 8);
        } else {
#pragma unroll
          for (int e = 0; e < 8; ++e) {
            bv0[e] = (col0 + bnq + e < N) ? (short)bp[e] : (short)0;
            bv1[e] = (col0 + bnq + 8 + e < N) ? (short)bp[8 + e] : (short)0;
          }
        }
      }
    }
    __syncthreads();
    *(short8v*)&As[am][akq] = av0;
    *(short8v*)&As[am][akq + 8] = av1;
    *(short8v*)&Bs[bk][bnq] = bv0;
    *(short8v*)&Bs[bk][bnq + 8] = bv1;
    __syncthreads();
    short8v af[4];
#pragma unroll
    for (int mt = 0; mt < 4; ++mt)
      af[mt] = *(const short8v*)&As[wm * 64 + mt * 16 + l15][lhi * 8];
#pragma unroll
    for (int ct = 0; ct < 4; ++ct) {
      union { short8v v; unsigned short u[8]; } bf;
      const int nn = wn * 64 + ct * 16 + l15;
#pragma unroll
      for (int j = 0; j < 8; ++j) bf.u[j] = Bs[lhi * 8 + j][nn];
#pragma unroll
      for (int mt = 0; mt < 4; ++mt)
        acc[mt][ct] = __builtin_amdgcn_mfma_f32_16x16x32_bf16(
            af[mt], bf.v, acc[mt][ct], 0, 0, 0);
    }
  }

#pragma unroll
  for (int mt = 0; mt < 4; ++mt) {
    const int rb = row0 + wm * 64 + mt * 16 + lhi * 4;
#pragma unroll
    for (int u = 0; u < 4; ++u) {
      const int r = rb + u;
      if (r >= M) continue;
#pragma unroll
      for (int ct = 0; ct < 4; ++ct) {
        const int c = col0 + wn * 64 + ct * 16 + l15;
        if (c >= N) continue;
        float val = acc[mt][ct][u];
        if (bias) val += bias[c];
        Cbf[(size_t)r * ldc + c] = f2bf(val);
      }
    }
  }
}

// Device body: N=100 GEMM (K=512) + fused row-softmax -> bf16 probs.
__device__ __forceinline__ void sm100_body(
    char* smem, const unsigned short* __restrict__ A,
    const unsigned short* __restrict__ B, const float* __restrict__ bias,
    unsigned short* __restrict__ obf, int lda, int ldb, int ldo, int rowblk) {
  unsigned short (*As)[40] = (unsigned short(*)[40])smem;
  unsigned short (*Bs)[132] = (unsigned short(*)[132])(smem + 10240);
  unsigned short (*Ps)[104] = (unsigned short(*)[104])smem;
  const int tid = threadIdx.x;
  const int l = tid & 63, w = tid >> 6;
  const int l15 = l & 15, lhi = l >> 4;
  const int wm = w >> 1, wn = w & 1;
  const int row0 = rowblk * 128;
  const int am = tid >> 1, akq = (tid & 1) << 4;
  const int bk = tid >> 3, bnq = (tid & 7) << 4;
  f32x4 acc[4][4] = {};

  for (int k0 = 0; k0 < DDIM; k0 += 32) {
    const unsigned short* ap = A + (size_t)(row0 + am) * lda + k0 + akq;
    short8v av0 = *(const short8v*)ap;
    short8v av1 = *(const short8v*)(ap + 8);
    short8v bv0 = {}, bv1 = {};
    const unsigned short* bp = B + (size_t)(k0 + bk) * ldb + bnq;
    if (bnq + 15 < MMEM) {
      bv0 = *(const short8v*)bp;
      bv1 = *(const short8v*)(bp + 8);
    } else {
#pragma unroll
      for (int e = 0; e < 8; ++e) {
        bv0[e] = (bnq + e < MMEM) ? (short)bp[e] : (short)0;
        bv1[e] = (bnq + 8 + e < MMEM) ? (short)bp[8 + e] : (short)0;
      }
    }
    __syncthreads();
    *(short8v*)&As[am][akq] = av0;
    *(short8v*)&As[am][akq + 8] = av1;
    *(short8v*)&Bs[bk][bnq] = bv0;
    *(short8v*)&Bs[bk][bnq + 8] = bv1;
    __syncthreads();
    short8v af[4];
#pragma unroll
    for (int mt = 0; mt < 4; ++mt)
      af[mt] = *(const short8v*)&As[wm * 64 + mt * 16 + l15][lhi * 8];
#pragma unroll
    for (int ct = 0; ct < 4; ++ct) {
      union { short8v v; unsigned short u[8]; } bf;
      const int nn = wn * 64 + ct * 16 + l15;
#pragma unroll
      for (int j = 0; j < 8; ++j) bf.u[j] = Bs[lhi * 8 + j][nn];
#pragma unroll
      for (int mt = 0; mt < 4; ++mt)
        acc[mt][ct] = __builtin_amdgcn_mfma_f32_16x16x32_bf16(
            af[mt], bf.v, acc[mt][ct], 0, 0, 0);
    }
  }

  __syncthreads();   // As/Bs dead; Ps overlays them
#pragma unroll
  for (int mt = 0; mt < 4; ++mt) {
#pragma unroll
    for (int u = 0; u < 4; ++u) {
      const int r = wm * 64 + mt * 16 + lhi * 4 + u;
#pragma unroll
      for (int ct = 0; ct < 4; ++ct) {
        const int c = wn * 64 + ct * 16 + l15;
        if (c < MMEM) {
          float val = acc[mt][ct][u];
          if (bias) val += bias[c];
          Ps[r][c] = f2bf(val);
        }
      }
    }
  }
  __syncthreads();
  for (int rr = 0; rr < 32; ++rr) {
    const int r = w * 32 + rr;
    float v0 = bf2f(Ps[r][l]);
    const bool has1 = (l + 64) < MMEM;
    float v1 = has1 ? bf2f(Ps[r][l + 64]) : -3.4e38f;
    float m = fmaxf(v0, v1);
#pragma unroll
    for (int o = 32; o; o >>= 1) m = fmaxf(m, __shfl_xor(m, o, 64));
    float e0 = expf(v0 - m);
    float e1 = has1 ? expf(v1 - m) : 0.f;
    float s = e0 + e1;
#pragma unroll
    for (int o = 32; o; o >>= 1) s += __shfl_xor(s, o, 64);
    float inv = 1.f / s;
    unsigned short* orow = obf + (size_t)(row0 + r) * ldo;
    orow[l] = f2bf(e0 * inv);
    if (has1) orow[l + 64] = f2bf(e1 * inv);
  }
}

// Device body: C(MxN) += A^T @ B over K-chunk (atomic f32 C).
__device__ __forceinline__ void atb_body(
    char* smem, const unsigned short* __restrict__ A,
    const unsigned short* __restrict__ B, float* __restrict__ C,
    int M, int N, int K, int lda, int ldb, int ldc, int KC,
    int bx, int by, int bz) {
  unsigned short (*As)[40] = (unsigned short(*)[40])smem;
  unsigned short (*Bs)[132] = (unsigned short(*)[132])(smem + 10240);
  const int tid = threadIdx.x;
  const int l = tid & 63, w = tid >> 6;
  const int l15 = l & 15, lhi = l >> 4;
  const int wm = w >> 1, wn = w & 1;
  const int row0 = by * 128, col0 = bx * 128;
  const int kbeg = bz * KC;
  const int kend = min(kbeg + KC, K);
  const int akk = tid >> 3, amq = (tid & 7) << 4;
  const int bk = tid >> 3, bnq = (tid & 7) << 4;
  f32x4 acc[4][4] = {};

  for (int k0 = kbeg; k0 < kend; k0 += 32) {
    unsigned short av[16]; short8v bv0 = {}, bv1 = {};
    {
      const int kk = k0 + akk;
      if (kk < kend) {
        const unsigned short* ap = A + (size_t)kk * lda + row0 + amq;
        if (row0 + amq + 15 < M) {
          *(short8v*)&av[0] = *(const short8v*)ap;
          *(short8v*)&av[8] = *(const short8v*)(ap + 8);
        } else {
#pragma unroll
          for (int e = 0; e < 16; ++e)
            av[e] = (row0 + amq + e < M) ? ap[e] : 0;
        }
      } else {
#pragma unroll
        for (int e = 0; e < 16; ++e) av[e] = 0;
      }
    }
    {
      const int kk = k0 + bk;
      if (kk < kend) {
        const unsigned short* bp = B + (size_t)kk * ldb + col0 + bnq;
        if (col0 + bnq + 15 < N) {
          bv0 = *(const short8v*)bp;
          bv1 = *(const short8v*)(bp + 8);
        } else {
#pragma unroll
          for (int e = 0; e < 8; ++e) {
            bv0[e] = (col0 + bnq + e < N) ? (short)bp[e] : (short)0;
            bv1[e] = (col0 + bnq + 8 + e < N) ? (short)bp[8 + e] : (short)0;
          }
        }
      }
    }
    __syncthreads();
#pragma unroll
    for (int e = 0; e < 16; ++e) As[amq + e][akk] = av[e];   // transposed
    *(short8v*)&Bs[bk][bnq] = bv0;
    *(short8v*)&Bs[bk][bnq + 8] = bv1;
    __syncthreads();
    short8v af[4];
#pragma unroll
    for (int mt = 0; mt < 4; ++mt)
      af[mt] = *(const short8v*)&As[wm * 64 + mt * 16 + l15][lhi * 8];
#pragma unroll
    for (int ct = 0; ct < 4; ++ct) {
      union { short8v v; unsigned short u[8]; } bf;
      const int nn = wn * 64 + ct * 16 + l15;
#pragma unroll
      for (int j = 0; j < 8; ++j) bf.u[j] = Bs[lhi * 8 + j][nn];
#pragma unroll
      for (int mt = 0; mt < 4; ++mt)
        acc[mt][ct] = __builtin_amdgcn_mfma_f32_16x16x32_bf16(
            af[mt], bf.v, acc[mt][ct], 0, 0, 0);
    }
  }

#pragma unroll
  for (int mt = 0; mt < 4; ++mt) {
    const int rb = row0 + wm * 64 + mt * 16 + lhi * 4;
#pragma unroll
    for (int u = 0; u < 4; ++u) {
      const int r = rb + u;
      if (r >= M) continue;
#pragma unroll
      for (int ct = 0; ct < 4; ++ct) {
        const int c = col0 + wn * 64 + ct * 16 + l15;
        if (c >= N) continue;
        atomicAdd(&C[(size_t)r * ldc + c], acc[mt][ct][u]);
      }
    }
  }
}

// ---------------------------------------------------------------------------
// step2: ip12 GEMM (blocks 0..1023) || ip3 GEMM+softmax (1024..1151)
__global__ __launch_bounds__(256) void step2_k(
    const unsigned short* __restrict__ qnbf, const unsigned short* __restrict__ Wcat,
    const float* __restrict__ bcat, unsigned short* __restrict__ ip12bf,
    const unsigned short* __restrict__ W3bf, const float* __restrict__ b3,
    unsigned short* __restrict__ ip3bf) {
  __shared__ char smem[26624];
  const int bid = blockIdx.x;
  if (bid < 1024) {
    gemm_body(smem, qnbf, Wcat, bcat, ip12bf, NTOK, 1024, DDIM,
              DDIM, 1024, 1024, bid & 7, bid >> 3);
  } else {
    sm100_body(smem, qnbf, W3bf, b3, ip3bf, DDIM, MMEM, MMEM, bid - 1024);
  }
}

// step3: atb_item (0..511) || atb_S (512..767) || colsum (768..1023)
__global__ __launch_bounds__(256) void step3_k(
    const unsigned short* __restrict__ ip12bf, const unsigned short* __restrict__ ip3bf,
    float* __restrict__ item, float* __restrict__ S, float* __restrict__ ip2sum) {
  __shared__ char smem[18688];
  const int bid = blockIdx.x;
  const int t = threadIdx.x;
  if (bid < 512) {
    atb_body(smem, ip12bf, ip12bf, item, DDIM, DDIM, NTOK,
             1024, 1024, DDIM, 512, bid & 3, (bid >> 2) & 3, bid >> 4);
  } else if (bid < 768) {
    const int b2 = bid - 512;
    atb_body(smem, ip3bf, ip12bf + 512, S, MMEM, DDIM, NTOK,
             MMEM, 1024, DDIM, 256, b2 & 3, 0, b2 >> 2);
  } else {
    const int cb = bid - 768;   // 0..255, 64 rows each
    const unsigned short* p = ip12bf + 512 + (size_t)cb * 64 * 1024 + t;
    float a0 = 0.f, a1 = 0.f, a2 = 0.f, a3 = 0.f;
    float b0 = 0.f, b1 = 0.f, b2 = 0.f, b3 = 0.f;
    for (int r = 0; r < 64; r += 4) {
      a0 += bf2f(p[(size_t)(r + 0) * 1024]); b0 += bf2f(p[(size_t)(r + 0) * 1024 + 256]);
      a1 += bf2f(p[(size_t)(r + 1) * 1024]); b1 += bf2f(p[(size_t)(r + 1) * 1024 + 256]);
      a2 += bf2f(p[(size_t)(r + 2) * 1024]); b2 += bf2f(p[(size_t)(r + 2) * 1024 + 256]);
      a3 += bf2f(p[(size_t)(r + 3) * 1024]); b3 += bf2f(p[(size_t)(r + 3) * 1024 + 256]);
    }
    atomicAdd(&ip2sum[t], (a0 + a1) + (a2 + a3));
    atomicAdd(&ip2sum[t + 256], (b0 + b1) + (b2 + b3));
  }
}

// ---------------------------------------------------------------------------
// ip4sum: 64 flat rows per block (800 blocks), 8 independent accumulators.
__global__ __launch_bounds__(256) void ip4sum_k(const float* __restrict__ S,
                                                const float* __restrict__ rel_w,
                                                float* __restrict__ out) {
  __shared__ float sv[64];
  int r0 = blockIdx.x * 64;
  int tid = threadIdx.x;
  if (tid < 64) sv[tid] = S[r0 + tid];
  __syncthreads();
  float a0 = 0.f, a1 = 0.f, a2 = 0.f, a3 = 0.f;
  float b0 = 0.f, b1 = 0.f, b2 = 0.f, b3 = 0.f;
  const float* base = rel_w + (size_t)r0 * DDIM;
  for (int r = 0; r < 64; r += 4) {
    const float* p0 = base + (size_t)(r + 0) * DDIM;
    const float* p1 = base + (size_t)(r + 1) * DDIM;
    const float* p2 = base + (size_t)(r + 2) * DDIM;
    const float* p3 = base + (size_t)(r + 3) * DDIM;
    a0 = fmaf(sv[r + 0], p0[tid], a0); b0 = fmaf(sv[r + 0], p0[tid + 256], b0);
    a1 = fmaf(sv[r + 1], p1[tid], a1); b1 = fmaf(sv[r + 1], p1[tid + 256], b1);
    a2 = fmaf(sv[r + 2], p2[tid], a2); b2 = fmaf(sv[r + 2], p2[tid + 256], b2);
    a3 = fmaf(sv[r + 3], p3[tid], a3); b3 = fmaf(sv[r + 3], p3[tid + 256], b3);
  }
  atomicAdd(&out[tid], (a0 + a1) + (a2 + a3));
  atomicAdd(&out[tid + 256], (b0 + b1) + (b2 + b3));
}

// ---------------------------------------------------------------------------
// qkv GEMM with fused item-assembly: A[r,k] = item[r,k]+item_w[r,k]+s4[r]*s2[k]
__global__ __launch_bounds__(256) void gemm_qkv_k(
    const float* __restrict__ item, const float* __restrict__ item_w,
    const float* __restrict__ s4, const float* __restrict__ s2,
    const unsigned short* __restrict__ B, const float* __restrict__ bias,
    float* __restrict__ C) {
  __shared__ unsigned short As[128][40];
  __shared__ unsigned short Bs[32][132];
  const int tid = threadIdx.x;
  const int l = tid & 63, w = tid >> 6;
  const int l15 = l & 15, lhi = l >> 4;
  const int wm = w >> 1, wn = w & 1;
  const int row0 = blockIdx.y * 128, col0 = blockIdx.x * 128;
  const int am = tid >> 1, akq = (tid & 1) << 4;
  const int bk = tid >> 3, bnq = (tid & 7) << 4;
  const int arow = row0 + am;
  f32x4 acc[4][4] = {};

  for (int k0 = 0; k0 < DDIM; k0 += 32) {
    float av[16];
    {
      const size_t off = (size_t)arow * DDIM + k0 + akq;
      const float s4r = s4[arow];
#pragma unroll
      for (int u = 0; u < 4; ++u) {
        float4 a = *(const float4*)(item + off + 4 * u);
        float4 b = *(const float4*)(item_w + off + 4 * u);
        float4 c = *(const float4*)(s2 + k0 + akq + 4 * u);
        av[4*u+0] = a.x + b.x + s4r * c.x;
        av[4*u+1] = a.y + b.y + s4r * c.y;
        av[4*u+2] = a.z + b.z + s4r * c.z;
        av[4*u+3] = a.w + b.w + s4r * c.w;
      }
    }
    short8v bv0 = {}, bv1 = {};
    {
      const int kk = k0 + bk;
      const unsigned short* bp = B + (size_t)kk * QKVW + col0 + bnq;
      if (col0 + bnq + 15 < QKVW) {
        bv0 = *(const short8v*)bp;
        bv1 = *(const short8v*)(bp + 8);
      } else {
#pragma unroll
        for (int e = 0; e < 8; ++e) {
          bv0[e] = (col0 + bnq + e < QKVW) ? (short)bp[e] : (short)0;
          bv1[e] = (col0 + bnq + 8 + e < QKVW) ? (short)bp[8 + e] : (short)0;
        }
      }
    }
    __syncthreads();
    {
      short8v p0, p1;
#pragma unroll
      for (int e = 0; e < 8; ++e) p0[e] = (short)f2bf(av[e]);
#pragma unroll
      for (int e = 0; e < 8; ++e) p1[e] = (short)f2bf(av[8 + e]);
      *(short8v*)&As[am][akq] = p0;
      *(short8v*)&As[am][akq + 8] = p1;
    }
    *(short8v*)&Bs[bk][bnq] = bv0;
    *(short8v*)&Bs[bk][bnq + 8] = bv1;
    __syncthreads();
    short8v af[4];
#pragma unroll
    for (int mt = 0; mt < 4; ++mt)
      af[mt] = *(const short8v*)&As[wm * 64 + mt * 16 + l15][lhi * 8];
#pragma unroll
    for (int ct = 0; ct < 4; ++ct) {
      union { short8v v; unsigned short u[8]; } bf;
      const int nn = wn * 64 + ct * 16 + l15;
#pragma unroll
      for (int j = 0; j < 8; ++j) bf.u[j] = Bs[lhi * 8 + j][nn];
#pragma unroll
      for (int mt = 0; mt < 4; ++mt)
        acc[mt][ct] = __builtin_amdgcn_mfma_f32_16x16x32_bf16(
            af[mt], bf.v, acc[mt][ct], 0, 0, 0);
    }
  }

#pragma unroll
  for (int mt = 0; mt < 4; ++mt) {
    const int rb = row0 + wm * 64 + mt * 16 + lhi * 4;
#pragma unroll
    for (int u = 0; u < 4; ++u) {
      const int r = rb + u;
#pragma unroll
      for (int ct = 0; ct < 4; ++ct) {
        const int c = col0 + wn * 64 + ct * 16 + l15;
        if (c >= QKVW) continue;
        C[(size_t)r * QKVW + c] = acc[mt][ct][u] + bias[c];
      }
    }
  }
}

// addr GEMM + softmax (standalone)
__global__ __launch_bounds__(256) void sm100_addr_k(
    const unsigned short* __restrict__ qnbf, const unsigned short* __restrict__ mnTbf,
    unsigned short* __restrict__ addrbf) {
  __shared__ char smem[26624];
  sm100_body(smem, qnbf, mnTbf, nullptr, addrbf, DDIM, MMEM, 128, blockIdx.x);
}

// ---------------------------------------------------------------------------
// mf GEMM writing out directly (channel-major) via LDS bf16 transpose epilogue.
__global__ __launch_bounds__(256) void gemm_mf_out_k(
    const unsigned short* __restrict__ A, const unsigned short* __restrict__ B,
    float* __restrict__ out) {
  __shared__ char smem[35328];
  unsigned short (*As)[40] = (unsigned short(*)[40])smem;
  unsigned short (*Bs)[132] = (unsigned short(*)[132])(smem + 10240);
  unsigned short (*Ps)[138] = (unsigned short(*)[138])smem;  // overlay after loop
  const int tid = threadIdx.x;
  const int l = tid & 63, w = tid >> 6;
  const int l15 = l & 15, lhi = l >> 4;
  const int wm = w >> 1, wn = w & 1;
  const int row0 = blockIdx.y * 128, col0 = blockIdx.x * 128;
  const int am = tid >> 1, akq = (tid & 1) << 4;
  const int bk = tid >> 3, bnq = (tid & 7) << 4;
  const int K = MMEM, lda = 128, ldb = DDIM;
  f32x4 acc[4][4] = {};

  for (int k0 = 0; k0 < 128; k0 += 32) {
    short8v av0 = {}, av1 = {}, bv0 = {}, bv1 = {};
    if (k0 + akq < K) {
      const unsigned short* ap = A + (size_t)(row0 + am) * lda + k0 + akq;
      if (k0 + akq + 15 < K) {
        av0 = *(const short8v*)ap;
        av1 = *(const short8v*)(ap + 8);
      } else {
#pragma unroll
        for (int e = 0; e < 8; ++e) {
          av0[e] = (k0 + akq + e < K) ? (short)ap[e] : (short)0;
          av1[e] = (k0 + akq + 8 + e < K) ? (short)ap[8 + e] : (short)0;
        }
      }
    }
    {
      const int kk = k0 + bk;
      if (kk < K) {
        const unsigned short* bp = B + (size_t)kk * ldb + col0 + bnq;
        bv0 = *(const short8v*)bp;
        bv1 = *(const short8v*)(bp + 8);
      }
    }
    __syncthreads();
    *(short8v*)&As[am][akq] = av0;
    *(short8v*)&As[am][akq + 8] = av1;
    *(short8v*)&Bs[bk][bnq] = bv0;
    *(short8v*)&Bs[bk][bnq + 8] = bv1;
    __syncthreads();
    short8v af[4];
#pragma unroll
    for (int mt = 0; mt < 4; ++mt)
      af[mt] = *(const short8v*)&As[wm * 64 + mt * 16 + l15][lhi * 8];
#pragma unroll
    for (int ct = 0; ct < 4; ++ct) {
      union { short8v v; unsigned short u[8]; } bf;
      const int nn = wn * 64 + ct * 16 + l15;
#pragma unroll
      for (int j = 0; j < 8; ++j) bf.u[j] = Bs[lhi * 8 + j][nn];
#pragma unroll
      for (int mt = 0; mt < 4; ++mt)
        acc[mt][ct] = __builtin_amdgcn_mfma_f32_16x16x32_bf16(
            af[mt], bf.v, acc[mt][ct], 0, 0, 0);
    }
  }

  __syncthreads();   // As/Bs dead; Ps overlays
#pragma unroll
  for (int mt = 0; mt < 4; ++mt) {
#pragma unroll
    for (int u = 0; u < 4; ++u) {
      const int r = wm * 64 + mt * 16 + lhi * 4 + u;   // hw within tile
#pragma unroll
      for (int ct = 0; ct < 4; ++ct) {
        const int c = wn * 64 + ct * 16 + l15;          // channel within tile
        Ps[r][c] = f2bf(acc[mt][ct][u]);
      }
    }
  }
  __syncthreads();
  const int b = row0 >> 12;
  const int hwb = row0 & 4095;
  const int j = tid & 63;
  float* obase = out + (size_t)b * 4194304 + (size_t)(512 + col0) * HWSZ + hwb;
  for (int cr = tid >> 6; cr < 128; cr += 4) {
    obase[(size_t)cr * HWSZ + j]      = bf2f(Ps[j][cr]);
    obase[(size_t)cr * HWSZ + j + 64] = bf2f(Ps[j + 64][cr]);
  }
}

// ---------------------------------------------------------------------------
// rel0 via MFMA (known-good)
__global__ __launch_bounds__(256) void rel0_mfma_k(
    const float* __restrict__ qm, const float* __restrict__ km,
    const float* __restrict__ vm, const float* __restrict__ rel_w,
    unsigned short* __restrict__ relbf) {
  __shared__ unsigned short Ts[128][136];
  __shared__ unsigned short Vs[128][136];
  __shared__ float qv[128];
  const int i = blockIdx.y;
  const int d0 = blockIdx.x * 128;
  const int tid = threadIdx.x;
  const int l = tid & 63, w = tid >> 6;
  const int l15 = l & 15, lhi = l >> 4;
  const int wm = w >> 1, wn = w & 1;

  if (tid < 128) qv[tid] = qm[(size_t)i * DDIM + d0 + tid];
  __syncthreads();
#pragma unroll
  for (int p = 0; p < 8; ++p) {
    int g = p * 2048 + tid * 8;
    int j = g >> 7, dd = g & 127;
    if (j < MMEM) {
      const float* kp = km + (size_t)j * DDIM + d0 + dd;
      float4 k0v = *(const float4*)kp;
      float4 k1v = *(const float4*)(kp + 4);
      float kv[8] = {k0v.x, k0v.y, k0v.z, k0v.w, k1v.x, k1v.y, k1v.z, k1v.w};
#pragma unroll
      for (int e = 0; e < 8; ++e)
        Ts[dd + e][j] = f2bf(tanhf(qv[dd + e] * kv[e]));
    } else {
#pragma unroll
      for (int e = 0; e < 8; ++e) Ts[dd + e][j] = 0;
    }
  }

  for (int f0 = 0; f0 < DDIM; f0 += 128) {
    __syncthreads();
#pragma unroll
    for (int p = 0; p < 8; ++p) {
      int g = p * 2048 + tid * 8;
      int j = g >> 7, ff = g & 127;
      short8v pv;
      if (j < MMEM) {
        const float* vp = vm + (size_t)j * DDIM + f0 + ff;
        float4 v0 = *(const float4*)vp;
        float4 v1 = *(const float4*)(vp + 4);
        pv[0] = (short)f2bf(v0.x); pv[1] = (short)f2bf(v0.y);
        pv[2] = (short)f2bf(v0.z); pv[3] = (short)f2bf(v0.w);
        pv[4] = (short)f2bf(v1.x); pv[5] = (short)f2bf(v1.y);
        pv[6] = (short)f2bf(v1.z); pv[7] = (short)f2bf(v1.w);
      } else {
#pragma unroll
        for (int e = 0; e < 8; ++e) pv[e] = 0;
      }
      *(short8v*)&Vs[j][ff] = pv;
    }
    __syncthreads();
    f32x4 acc[4][4] = {};
#pragma unroll
    for (int ks = 0; ks < 4; ++ks) {
      const int kb = ks * 32;
      short8v af[4];
#pragma unroll
      for (int mt = 0; mt < 4; ++mt)
        af[mt] = *(const short8v*)&Ts[wm * 64 + mt * 16 + l15][kb + lhi * 8];
#pragma unroll
      for (int ct = 0; ct < 4; ++ct) {
        union { short8v v; unsigned short u[8]; } bf;
        const int nn = wn * 64 + ct * 16 + l15;
#pragma unroll
        for (int jj = 0; jj < 8; ++jj) bf.u[jj] = Vs[kb + lhi * 8 + jj][nn];
#pragma unroll
        for (int mt = 0; mt < 4; ++mt)
          acc[mt][ct] = __builtin_amdgcn_mfma_f32_16x16x32_bf16(
              af[mt], bf.v, acc[mt][ct], 0, 0, 0);
      }
    }
#pragma unroll
    for (int mt = 0; mt < 4; ++mt) {
#pragma unroll
      for (int u = 0; u < 4; ++u) {
        const int d = d0 + wm * 64 + mt * 16 + lhi * 4 + u;
        const size_t base = (size_t)i * 262144 + (size_t)d * DDIM;
#pragma unroll
        for (int ct = 0; ct < 4; ++ct) {
          const int f = f0 + wn * 64 + ct * 16 + l15;
          relbf[base + f] = f2bf(rel_w[base + f] + acc[mt][ct][u]);
        }
      }
    }
  }
}

// ---------------------------------------------------------------------------
// memgemm: 1024 threads (16 waves), KC=1024, 256 chunks, bf16 partials.
#define MGK 262144
#define MGKC 1024
#define MGCHUNK 256
__global__ __launch_bounds__(1024, 4) void memgemm_k(
    const unsigned short* __restrict__ Ag, const float* __restrict__ Bg,
    unsigned short* __restrict__ partial) {
  __shared__ unsigned short As[128][44];
  __shared__ unsigned short Bs[32][520];
  const int tid = threadIdx.x;
  const int l = tid & 63, w = tid >> 6;
  const int l15 = l & 15, lhi = l >> 4;
  const int kbeg = blockIdx.x * MGKC;
  const int arow = tid >> 3, akq = tid & 7;
  const int bk = tid >> 5, bnq = (tid & 31) * 16;
  const int bsw = ((bk >> 3) & 3) << 4;
  const int csw = lhi << 4;
  f32x4 acc[8][2] = {};

  for (int t32 = 0; t32 < MGKC / 32; ++t32) {
    const int kb = kbeg + t32 * 32;
    short4v av = {};
    if (arow < MMEM)
      av = *(const short4v*)(Ag + (size_t)arow * MGK + kb + akq * 4);
    float4 bv[4];
    const float* bp = Bg + (size_t)(kb + bk) * DDIM + bnq;
#pragma unroll
    for (int u = 0; u < 4; ++u) bv[u] = *(const float4*)(bp + 4 * u);
    __syncthreads();
    *(short4v*)&As[arow][akq * 4] = av;
#pragma unroll
    for (int u = 0; u < 2; ++u) {
      short8v pb;
      pb[0] = (short)f2bf(bv[2*u].x);   pb[1] = (short)f2bf(bv[2*u].y);
      pb[2] = (short)f2bf(bv[2*u].z);   pb[3] = (short)f2bf(bv[2*u].w);
      pb[4] = (short)f2bf(bv[2*u+1].x); pb[5] = (short)f2bf(bv[2*u+1].y);
      pb[6] = (short)f2bf(bv[2*u+1].z); pb[7] = (short)f2bf(bv[2*u+1].w);
      *(short8v*)&Bs[bk][(bnq + u * 8) ^ bsw] = pb;
    }
    __syncthreads();
    union { short8v v; unsigned short u[8]; } bf0, bf1;
    const int nn0 = w * 32 + l15, nn1 = w * 32 + 16 + l15;
#pragma unroll
    for (int j = 0; j < 8; ++j) {
      bf0.u[j] = Bs[lhi * 8 + j][nn0 ^ csw];
      bf1.u[j] = Bs[lhi * 8 + j][nn1 ^ csw];
    }
#pragma unroll
    for (int mt = 0; mt < 8; ++mt) {
      short8v af = *(const short8v*)&As[mt * 16 + l15][lhi * 8];
      acc[mt][0] = __builtin_amdgcn_mfma_f32_16x16x32_bf16(af, bf0.v, acc[mt][0], 0, 0, 0);
      acc[mt][1] = __builtin_amdgcn_mfma_f32_16x16x32_bf16(af, bf1.v, acc[mt][1], 0, 0, 0);
    }
  }

  unsigned short* pw = partial + (size_t)blockIdx.x * (MMEM * DDIM);
#pragma unroll
  for (int mt = 0; mt < 8; ++mt) {
    const int r0 = mt * 16 + lhi * 4;
#pragma unroll
    for (int r = 0; r < 4; ++r) {
      const int row = r0 + r;
      if (row < MMEM) {
        pw[(size_t)row * DDIM + w * 32 + l15]      = f2bf(acc[mt][0][r]);
        pw[(size_t)row * DDIM + w * 32 + 16 + l15] = f2bf(acc[mt][1][r]);
      }
    }
  }
}

// Fused reduce(256 bf16 partials) + br1 + l2norm -> mnbf/mnTbf (16 accumulators).
__global__ __launch_bounds__(512) void reduce_mn_k(
    const unsigned short* __restrict__ partial, const float* __restrict__ br1,
    unsigned short* __restrict__ mnbf, unsigned short* __restrict__ mnTbf) {
  __shared__ float r1[8];
  const int i = blockIdx.x, t = threadIdx.x;
  const unsigned short* p = partial + (size_t)i * DDIM + t;
  float a[16] = {};
  const size_t zs = (size_t)(MMEM * DDIM);
  for (int z = 0; z < MGCHUNK; z += 16) {
#pragma unroll
    for (int e = 0; e < 16; ++e) a[e] += bf2f(p[(z + e) * zs]);
  }
  float s = br1[t];
#pragma unroll
  for (int e = 0; e < 16; ++e) s += a[e];
  float q = s * s;
#pragma unroll
  for (int o = 32; o; o >>= 1) q += __shfl_xor(q, o, 64);
  if ((t & 63) == 0) r1[t >> 6] = q;
  __syncthreads();
  q = 0.f;
#pragma unroll
  for (int j = 0; j < 8; ++j) q += r1[j];
  float inv = 1.f / fmaxf(sqrtf(q), 1e-12f);
  unsigned short hv = f2bf(s * inv);
  mnbf[(size_t)i * DDIM + t] = hv;
  mnTbf[(size_t)t * MMEM + i] = hv;
}

// ---------------------------------------------------------------------------
// LayerNorm(len 300, eps=512) + direct scatter into qm/km/vm (M x D each)
__global__ __launch_bounds__(256) void ln300_k(const float* __restrict__ x,
                                               const float* __restrict__ g,
                                               const float* __restrict__ bb,
                                               float* __restrict__ qm,
                                               float* __restrict__ km,
                                               float* __restrict__ vm) {
  __shared__ float r1[4], r2[4];
  int row = blockIdx.x, tid = threadIdx.x;
  const float* xr = x + (size_t)row * QKVW;
  float v1 = xr[tid];
  float v2 = (tid + 256 < QKVW) ? xr[tid + 256] : 0.f;
  float s = v1 + v2, q = v1 * v1 + v2 * v2;
#pragma unroll
  for (int o = 32; o; o >>= 1) { s += __shfl_xor(s, o, 64); q += __shfl_xor(q, o, 64); }
  if ((tid & 63) == 0) { r1[tid >> 6] = s; r2[tid >> 6] = q; }
  __syncthreads();
  s = r1[0] + r1[1] + r1[2] + r1[3];
  q = r2[0] + r2[1] + r2[2] + r2[3];
  float mean = s * (1.f / 300.f);
  float var = q * (1.f / 300.f) - mean * mean;
  float inv = rsqrtf(var + 512.0f);
  float y1 = (v1 - mean) * inv * g[tid] + bb[tid];
  int j = tid;
  if (j < 100)      qm[(size_t)j * DDIM + row] = y1;
  else if (j < 200) km[(size_t)(j - 100) * DDIM + row] = y1;
  else              vm[(size_t)(j - 200) * DDIM + row] = y1;
  if (tid + 256 < QKVW) {
    float y2 = (v2 - mean) * inv * g[tid + 256] + bb[tid + 256];
    vm[(size_t)(tid + 56) * DDIM + row] = y2;   // j2-200 = tid+56
  }
}

// ---------------------------------------------------------------------------
extern "C" void kernel_launch(void* const* d_in, const int* in_sizes, int n_in,
                              void* d_out, int out_size, void* d_ws, size_t ws_size,
                              hipStream_t stream) {
  (void)in_sizes; (void)n_in; (void)out_size; (void)ws_size;
  const float* fea    = (const float*)d_in[0];
  const float* item_w = (const float*)d_in[1];
  const float* rel_w  = (const float*)d_in[2];
  const float* W1     = (const float*)d_in[3];
  const float* b1     = (const float*)d_in[4];
  const float* W2     = (const float*)d_in[5];
  const float* b2     = (const float*)d_in[6];
  const float* W3     = (const float*)d_in[7];
  const float* b3     = (const float*)d_in[8];
  const float* Wqkv   = (const float*)d_in[9];
  const float* bqkv   = (const float*)d_in[10];
  const float* ln_g   = (const float*)d_in[11];
  const float* ln_b   = (const float*)d_in[12];
  const float* Wr1    = (const float*)d_in[13];
  const float* br1    = (const float*)d_in[14];
  float* out = (float*)d_out;
  float* ws = (float*)d_ws;

  // f32 region (S..item contiguous: zeroed by feat_cvtw blocks 741+)
  float* S       = ws;                         // 51,200
  float* ip4sum  = S       + 51200;            // 512
  float* ip2sum  = ip4sum  + 512;              // 512
  float* item    = ip2sum  + 512;              // 262,144
  float* qkv     = item    + 262144;           // 153,600
  float* qm      = qkv     + 153600;           // 51,200
  float* km      = qm      + 51200;            // 51,200
  float* vm      = km      + 51200;            // 51,200
  float* bcat    = vm      + 51200;            // 1,024
  // u16 region
  unsigned short* u16base = (unsigned short*)(bcat + 1024);
  unsigned short* partial = u16base;                 // 13,107,200 u16 (256 chunks)
  unsigned short* qnbf    = partial + 13107200;      // 8,388,608
  unsigned short* ip12bf  = qnbf    + 8388608;       // 16,777,216 (ld 1024)
  unsigned short* ip3bf   = ip12bf  + 16777216;      // 1,638,400 (ld 100)
  unsigned short* addrbf  = ip3bf   + 1638400;       // 2,097,152 (ld 128)
  unsigned short* relbf   = addrbf  + 2097152;       // 26,214,400
  unsigned short* mnbf    = relbf   + 26214400;      // 51,200
  unsigned short* mnTbf   = mnbf    + 51200;         // 51,200
  unsigned short* Wcat    = mnTbf   + 51200;         // 524,288
  unsigned short* W3bf    = Wcat    + 524288;        // 51,200
  unsigned short* Wqbf    = W3bf    + 51200;         // 153,600

  // 1) fused: fea copy + qnbf + weight cvt + zero atomic targets
  feat_cvtw_k<<<1048, 256, 0, stream>>>(fea, qnbf, out, W1, W2, W3, Wqkv,
                                        b1, b2, Wcat, W3bf, Wqbf, bcat, S);

  // 2) merged: ip12 GEMM || ip3 GEMM+softmax
  step2_k<<<1152, 256, 0, stream>>>(qnbf, Wcat, bcat, ip12bf, W3bf, b3, ip3bf);

  // 3) merged: item = ip1^T@ip1 || S = ip3^T@ip2 || colsum(ip2)
  step3_k<<<1024, 256, 0, stream>>>(ip12bf, ip3bf, item, S, ip2sum);

  // 3b) ip4sum (needs S)
  ip4sum_k<<<800, 256, 0, stream>>>(S, rel_w, ip4sum);

  // 4+5) qkv = (item + item_w + outer) @ Wqbf + bqkv; LN + split
  gemm_qkv_k<<<dim3(3, 4), 256, 0, stream>>>(item, item_w, ip4sum, ip2sum,
                                             Wqbf, bqkv, qkv);
  ln300_k<<<512, 256, 0, stream>>>(qkv, ln_g, ln_b, qm, km, vm);

  // 6) relbf = bf16(rel_w + einsum(tanh(q*k), v))
  rel0_mfma_k<<<dim3(4, MMEM), 256, 0, stream>>>(qm, km, vm, rel_w, relbf);

  // 7) memory = relbf @ Wr1 (bf16 partials); reduce + l2norm
  memgemm_k<<<dim3(MGCHUNK), 1024, 0, stream>>>(relbf, Wr1, partial);
  reduce_mn_k<<<MMEM, 512, 0, stream>>>(partial, br1, mnbf, mnTbf);

  // 8) addr = softmax(qnbf@mnTbf); mf = addrbf@mnbf -> out directly
  sm100_addr_k<<<128, 256, 0, stream>>>(qnbf, mnTbf, addrbf);
  gemm_mf_out_k<<<dim3(4, 128), 256, 0, stream>>>(addrbf, mnbf, out);
}